// Round 6
// baseline (1117.929 us; speedup 1.0000x reference)
//
#include <hip/hip_runtime.h>
#include <cstddef>
#include <cstdint>

typedef unsigned short u16;
typedef signed char s8;
typedef short bf16x8 __attribute__((ext_vector_type(8)));
typedef float f32x4 __attribute__((ext_vector_type(4)));
typedef int i32x4 __attribute__((ext_vector_type(4)));

// Problem constants (B=16, S=1024, D=768, DC=64, K=8192)
#define NROW   16384
#define DMODEL 768
#define DCODE  64
#define KCODES 8192

// d_out layout (float element offsets): [out 16384*768][loss 1][codex 16384*8192]
#define OUT_LOSS  12582912
#define OUT_CODEX 12582913
// 16B-aligned scratch carved out of the codex region (fully overwritten by the
// one-hot writer at the end). All offsets in float units, multiples of 4.
// *** ORDERING INVARIANT: anything stored here (esp. P) must be fully consumed
// *** by dispatches that COMPLETE before onehot_k launches. Fusing a consumer
// *** of P with the one-hot writer races across blocks (round-5 failure).
#define S0        12582916
#define H_OFF     (S0)                        // 12582912 f
#define P_OFF     (H_OFF + 12582912)          // 6291456 f
#define ZN_OFF    (P_OFF + 6291456)           // 1048576 f
#define Q_OFF     (ZN_OFF + 1048576)          // 524288 f
#define ZH_OFF    (Q_OFF + 524288)            // u16 planes of Z: each 12582912 u16 = 6291456 f
#define ZM_OFF    (ZH_OFF + 6291456)
#define ZL_OFF    (ZM_OFF + 6291456)
#define W1H_OFF   (ZL_OFF + 6291456)          // W1^T planes: each 589824 u16 = 294912 f
#define W1M_OFF   (W1H_OFF + 294912)
#define W1L_OFF   (W1M_OFF + 294912)
#define NH_OFF    (W1L_OFF + 294912)          // Zn i8 planes: each 1048576 B (region sized for 2x)
#define NM_OFF    (NH_OFF + 524288)
#define NL_OFF    (NM_OFF + 524288)
#define EH_OFF    (NL_OFF + 524288)           // emb i8 planes: each 524288 B (region sized for 2x)
#define EM_OFF    (EH_OFF + 262144)
#define EL_OFF    (EM_OFF + 262144)

__device__ __forceinline__ u16 f2bf(float x) {
    unsigned u = __float_as_uint(x);
    u += 0x7fffu + ((u >> 16) & 1u);          // RTNE
    return (u16)(u >> 16);
}
__device__ __forceinline__ float bf2f(u16 h) {
    return __uint_as_float(((unsigned)h) << 16);
}

// Exact 24-bit fixed-point split (scale 2^22, |x|<=1): x_q = h*2^16 + m*2^8 + l
__device__ __forceinline__ void f2i8x3(float x, int& h, int& m, int& l) {
    int q = (int)rintf(x * 4194304.0f);       // 2^22
    l = (q << 24) >> 24;
    int t = (q - l) >> 8;
    m = (t << 24) >> 24;
    h = (t - m) >> 8;                         // |h| <= 64
}

// async global->LDS, 16 B per lane. LDS dest is wave-uniform base + lane*16
// (m104/m108): callers must pass lds = base + lane*16 exactly.
typedef __attribute__((address_space(1))) const unsigned int gas_u32;
typedef __attribute__((address_space(3))) unsigned int las_u32;
__device__ __forceinline__ void gll16(const void* g, void* l) {
    __builtin_amdgcn_global_load_lds((gas_u32*)g, (las_u32*)l, 16, 0, 0);
}

// ---------------------------------------------------------------------------
// Fused preprocessing (one launch, block-range partitioned; all parts
// independent, per-block code identical to the previous separate kernels):
//   blocks [0, 6144)      : split Z -> 3 bf16 planes
//   blocks [6144, 6720)   : split+transpose W1 -> 3 bf16 planes (24x24 tiles)
//   blocks [6720, 8768)   : emb -> i8x3 planes + Q = LN(emb)*gamma+beta
// Block 6144 thread 0 also zeroes the loss accumulator (replaces memset).
// ---------------------------------------------------------------------------
__global__ __launch_bounds__(256) void prep_k(
        const float* __restrict__ Z,
        u16* __restrict__ Ph, u16* __restrict__ Pm, u16* __restrict__ Pl,
        const float* __restrict__ W1,
        u16* __restrict__ Th, u16* __restrict__ Tm, u16* __restrict__ Tl,
        const float* __restrict__ emb,
        const float* __restrict__ gamma, const float* __restrict__ beta,
        s8* __restrict__ E0, s8* __restrict__ E1, s8* __restrict__ E2,
        float* __restrict__ Q, float* __restrict__ loss) {
    __shared__ float tile[32][33];
    const int b = blockIdx.x;
    const int t = threadIdx.x;

    if (b < 6144) {
        // ---- split_z ----
        const size_t g = (size_t)b * 256 + t;   // x8 elements
        const float4* zp = reinterpret_cast<const float4*>(Z) + g * 2;
        float4 a = zp[0], bb = zp[1];
        float xs[8] = {a.x, a.y, a.z, a.w, bb.x, bb.y, bb.z, bb.w};
        union { u16 u[8]; uint4 v; } ph, pm, pl;
#pragma unroll
        for (int k = 0; k < 8; ++k) {
            float x = xs[k];
            u16 h = f2bf(x); float r = x - bf2f(h);
            u16 m = f2bf(r); float r2 = r - bf2f(m);
            u16 l = f2bf(r2);
            ph.u[k] = h; pm.u[k] = m; pl.u[k] = l;
        }
        *reinterpret_cast<uint4*>(Ph + g * 8) = ph.v;
        *reinterpret_cast<uint4*>(Pm + g * 8) = pm.v;
        *reinterpret_cast<uint4*>(Pl + g * 8) = pl.v;
    } else if (b < 6720) {
        // ---- split_w1t ----
        if (b == 6144 && t == 0) *loss = 0.0f;
        const int bb = b - 6144;
        const int k0 = (bb / 24) * 32, n0 = (bb % 24) * 32;
        const int tc = t & 31, tr = t >> 5;          // tr 0..7
#pragma unroll
        for (int rr = 0; rr < 4; ++rr) {
            int r = tr * 4 + rr;
            tile[r][tc] = W1[(size_t)(k0 + r) * 768 + n0 + tc];
        }
        __syncthreads();
#pragma unroll
        for (int rr = 0; rr < 4; ++rr) {
            int n = n0 + tr * 4 + rr;
            int k = k0 + tc;
            float x = tile[tc][tr * 4 + rr];
            u16 h = f2bf(x); float r = x - bf2f(h);
            u16 m = f2bf(r); u16 l = f2bf(r - bf2f(m));
            Th[(size_t)n * 768 + k] = h;
            Tm[(size_t)n * 768 + k] = m;
            Tl[(size_t)n * 768 + k] = l;
        }
    } else {
        // ---- qln_emb ----
        const int bb = b - 6720;
        const int lane = t & 63;
        const int n = bb * 4 + (t >> 6);
        float x = emb[(size_t)n * 64 + lane];
        int h8, m8, l8;
        f2i8x3(x, h8, m8, l8);
        E0[(size_t)n * 64 + lane] = (s8)h8;
        E1[(size_t)n * 64 + lane] = (s8)m8;
        E2[(size_t)n * 64 + lane] = (s8)l8;
        float mu = x;
#pragma unroll
        for (int off = 32; off > 0; off >>= 1) mu += __shfl_xor(mu, off, 64);
        mu *= (1.0f / 64.0f);
        float d = x - mu;
        float var = d * d;
#pragma unroll
        for (int off = 32; off > 0; off >>= 1) var += __shfl_xor(var, off, 64);
        var *= (1.0f / 64.0f);
        Q[(size_t)n * 64 + lane] = d * rsqrtf(var + 1e-5f) * gamma[lane] + beta[lane];
    }
}

// ---------------------------------------------------------------------------
// GEMM1 via 6-product bf16x3 MFMA: H = tanh(Z @ W1 + b1).
// M=16384, N=768, K=768. BM=128, BN=192, BK=32. 512 blocks = 2/CU, no tail.
// Per-element accumulation order fixed -> bitwise-stable H across rounds.
// ---------------------------------------------------------------------------
#define APL 4096    // u16 per 128x32 A plane tile
#define BPL 6144    // u16 per 192x32 B plane tile
#define BOFF (3 * APL)
__global__ __launch_bounds__(256, 2) void gemm1_mfma(
        const u16* __restrict__ Ah0, const u16* __restrict__ Am0, const u16* __restrict__ Al0,
        const u16* __restrict__ Bh0, const u16* __restrict__ Bm0, const u16* __restrict__ Bl0,
        const float* __restrict__ bias, float* __restrict__ H) {
    __shared__ u16 lds[3 * APL + 3 * BPL];    // A planes then B planes (61440 B)

    // 512 blocks: xcd = b&7, ii = b>>3 (0..63). Each XCD: 16 row-tiles x 4 col-tiles.
    const int b = blockIdx.x;
    const int xcd = b & 7, ii = b >> 3;
    const int row0 = (xcd * 16 + (ii & 15)) * 128;
    const int col0 = (ii >> 4) * 192;

    const int t = threadIdx.x;
    const int w = t >> 6, lane = t & 63, lm = lane & 15, q = lane >> 4;
    const int wr = (w >> 1) * 64, wc = (w & 1) * 96;

    const u16* Ap[3] = {Ah0, Am0, Al0};
    const u16* Bp[3] = {Bh0, Bm0, Bl0};

    // staging geometry: each wave-instruction covers 16 rows x 4 chunks(16B)
    const int sr  = lane >> 2;        // row within 16-row group
    const int scc = lane & 3;         // LDS chunk slot

    f32x4 acc[4][6];
#pragma unroll
    for (int i = 0; i < 4; ++i)
#pragma unroll
        for (int j = 0; j < 6; ++j) acc[i][j] = (f32x4){0.f, 0.f, 0.f, 0.f};

    for (int k0 = 0; k0 < 768; k0 += 32) {
        __syncthreads();
#pragma unroll
        for (int p = 0; p < 3; ++p) {
#pragma unroll
            for (int rr = 0; rr < 2; ++rr) {      // A: 8 groups of 16 rows
                int g = rr * 4 + w;
                int r = g * 16 + sr;              // local row 0..127
                int cg = scc ^ ((r >> 1) & 3);    // swizzled source chunk
                gll16(Ap[p] + (size_t)(row0 + r) * 768 + k0 + cg * 8,
                      &lds[p * APL + g * 512 + lane * 8]);
            }
#pragma unroll
            for (int rr = 0; rr < 3; ++rr) {      // B: 12 groups of 16 rows
                int g = rr * 4 + w;
                int r = g * 16 + sr;              // local row 0..191
                int cg = scc ^ ((r >> 1) & 3);
                gll16(Bp[p] + (size_t)(col0 + r) * 768 + k0 + cg * 8,
                      &lds[BOFF + p * BPL + g * 512 + lane * 8]);
            }
        }
        __syncthreads();

        bf16x8 fah[4], fam[4], fal[4];
#pragma unroll
        for (int i = 0; i < 4; ++i) {
            int r = wr + i * 16 + lm;
            int off = r * 32 + ((q ^ ((r >> 1) & 3)) * 8);
            fah[i] = *reinterpret_cast<const bf16x8*>(&lds[0 * APL + off]);
            fam[i] = *reinterpret_cast<const bf16x8*>(&lds[1 * APL + off]);
            fal[i] = *reinterpret_cast<const bf16x8*>(&lds[2 * APL + off]);
        }
#pragma unroll
        for (int j = 0; j < 6; ++j) {
            int rb = wc + j * 16 + lm;            // 0..191
            int offb = rb * 32 + ((q ^ ((rb >> 1) & 3)) * 8);
            bf16x8 fbh = *reinterpret_cast<const bf16x8*>(&lds[BOFF + 0 * BPL + offb]);
            bf16x8 fbm = *reinterpret_cast<const bf16x8*>(&lds[BOFF + 1 * BPL + offb]);
            bf16x8 fbl = *reinterpret_cast<const bf16x8*>(&lds[BOFF + 2 * BPL + offb]);
#pragma unroll
            for (int i = 0; i < 4; ++i) {
                f32x4 c = acc[i][j];
                c = __builtin_amdgcn_mfma_f32_16x16x32_bf16(fah[i], fbl, c, 0, 0, 0);
                c = __builtin_amdgcn_mfma_f32_16x16x32_bf16(fal[i], fbh, c, 0, 0, 0);
                c = __builtin_amdgcn_mfma_f32_16x16x32_bf16(fam[i], fbm, c, 0, 0, 0);
                c = __builtin_amdgcn_mfma_f32_16x16x32_bf16(fah[i], fbm, c, 0, 0, 0);
                c = __builtin_amdgcn_mfma_f32_16x16x32_bf16(fam[i], fbh, c, 0, 0, 0);
                c = __builtin_amdgcn_mfma_f32_16x16x32_bf16(fah[i], fbh, c, 0, 0, 0);
                acc[i][j] = c;
            }
        }
    }
    // epilogue: +bias, tanh, store
#pragma unroll
    for (int i = 0; i < 4; ++i)
#pragma unroll
        for (int j = 0; j < 6; ++j) {
            int col = col0 + wc + j * 16 + lm;
            float bv = bias[col];
#pragma unroll
            for (int r = 0; r < 4; ++r) {
                int row = row0 + wr + i * 16 + q * 4 + r;
                H[(size_t)row * 768 + col] = tanhf(acc[i][j][r] + bv);
            }
        }
}

// ---------------------------------------------------------------------------
// GEMM2 fused with l2norm: Zn = l2norm(H @ W2 + b2), also writes Zn i8x3
// fixed-point planes (|Zn_i| <= 1 -> exact 24-bit quantization).
// M=16384, N=64(full), K=768. fp32 vector.
// ---------------------------------------------------------------------------
__global__ __launch_bounds__(256) void gemm2_l2(const float* __restrict__ A,
                                                const float* __restrict__ B,
                                                const float* __restrict__ bias,
                                                float* __restrict__ Zn,
                                                s8* __restrict__ Z0,
                                                s8* __restrict__ Z1,
                                                s8* __restrict__ Z2) {
    __shared__ float As[16][64];
    __shared__ float Bs[16][64];
    const int t    = threadIdx.x;
    const int row0 = blockIdx.x * 64;
    const int tx = t & 15, ty = t >> 4;
    const int ar = t >> 2, ac = (t & 3) << 2;
    const int br = t >> 4, bc = (t & 15) << 2;

    const float* Ap = A + (size_t)(row0 + ar) * 768 + ac;
    const float* Bp = B + (size_t)br * 64 + bc;

    float acc[4][4];
#pragma unroll
    for (int i = 0; i < 4; ++i)
#pragma unroll
        for (int j = 0; j < 4; ++j) acc[i][j] = 0.0f;

    for (int k0 = 0; k0 < 768; k0 += 16) {
        float4 a0 = *reinterpret_cast<const float4*>(Ap + k0);
        float4 b0 = *reinterpret_cast<const float4*>(Bp + (size_t)k0 * 64);
        __syncthreads();
        As[ac + 0][ar] = a0.x; As[ac + 1][ar] = a0.y;
        As[ac + 2][ar] = a0.z; As[ac + 3][ar] = a0.w;
        *reinterpret_cast<float4*>(&Bs[br][bc]) = b0;
        __syncthreads();
#pragma unroll
        for (int k = 0; k < 16; ++k) {
            float4 xa = *reinterpret_cast<const float4*>(&As[k][ty << 2]);
            float4 xb = *reinterpret_cast<const float4*>(&Bs[k][tx << 2]);
            float av[4] = {xa.x, xa.y, xa.z, xa.w};
            float bv[4] = {xb.x, xb.y, xb.z, xb.w};
#pragma unroll
            for (int i = 0; i < 4; ++i)
#pragma unroll
                for (int j = 0; j < 4; ++j)
                    acc[i][j] = fmaf(av[i], bv[j], acc[i][j]);
        }
    }
    const int c = tx << 2;
    const float4 bv4 = *reinterpret_cast<const float4*>(bias + c);
#pragma unroll
    for (int i = 0; i < 4; ++i) {
        float v0 = acc[i][0] + bv4.x;
        float v1 = acc[i][1] + bv4.y;
        float v2 = acc[i][2] + bv4.z;
        float v3 = acc[i][3] + bv4.w;
        float ss = v0 * v0 + v1 * v1 + v2 * v2 + v3 * v3;
#pragma unroll
        for (int msk = 1; msk <= 8; msk <<= 1) ss += __shfl_xor(ss, msk, 64);
        float sc = 1.0f / fmaxf(sqrtf(ss), 1e-12f);
        v0 *= sc; v1 *= sc; v2 *= sc; v3 *= sc;
        int r = row0 + (ty << 2) + i;
        float4 z = {v0, v1, v2, v3};
        *reinterpret_cast<float4*>(Zn + (size_t)r * 64 + c) = z;
        float vs[4] = {v0, v1, v2, v3};
        unsigned pk0 = 0, pk1 = 0, pk2 = 0;
#pragma unroll
        for (int j = 0; j < 4; ++j) {
            int h8, m8, l8;
            f2i8x3(vs[j], h8, m8, l8);
            pk0 |= ((unsigned)(unsigned char)(s8)h8) << (8 * j);
            pk1 |= ((unsigned)(unsigned char)(s8)m8) << (8 * j);
            pk2 |= ((unsigned)(unsigned char)(s8)l8) << (8 * j);
        }
        *reinterpret_cast<unsigned*>(Z0 + (size_t)r * 64 + c) = pk0;
        *reinterpret_cast<unsigned*>(Z1 + (size_t)r * 64 + c) = pk1;
        *reinterpret_cast<unsigned*>(Z2 + (size_t)r * 64 + c) = pk2;
    }
}

// ---------------------------------------------------------------------------
// Generic 128x128x16 fp32 tiled GEMM (used for P = Q @ Wp + bp, K=64).
// ---------------------------------------------------------------------------
__global__ __launch_bounds__(256) void gemm128(const float* __restrict__ A,
                                               const float* __restrict__ B,
                                               const float* __restrict__ bias,
                                               float* __restrict__ C,
                                               int M, int N, int K) {
    __shared__ float As[16][128];
    __shared__ float Bs[16][128];
    const int t    = threadIdx.x;
    const int row0 = blockIdx.y * 128;
    const int col0 = blockIdx.x * 128;
    const int tx = t & 15, ty = t >> 4;
    const int ar = t >> 2, ac = (t & 3) << 2;
    const int br = t >> 5, bc = (t & 31) << 2;

    const float* Ap0 = A + (size_t)(row0 + ar) * K + ac;
    const float* Ap1 = Ap0 + (size_t)64 * K;
    const float* Bp0 = B + (size_t)br * N + col0 + bc;
    const float* Bp1 = Bp0 + (size_t)8 * N;

    float acc[8][8];
#pragma unroll
    for (int i = 0; i < 8; ++i)
#pragma unroll
        for (int j = 0; j < 8; ++j) acc[i][j] = 0.0f;

    for (int k0 = 0; k0 < K; k0 += 16) {
        float4 a0 = *reinterpret_cast<const float4*>(Ap0 + k0);
        float4 a1 = *reinterpret_cast<const float4*>(Ap1 + k0);
        float4 b0 = *reinterpret_cast<const float4*>(Bp0 + (size_t)k0 * N);
        float4 b1 = *reinterpret_cast<const float4*>(Bp1 + (size_t)k0 * N);
        __syncthreads();
        As[ac + 0][ar] = a0.x; As[ac + 1][ar] = a0.y;
        As[ac + 2][ar] = a0.z; As[ac + 3][ar] = a0.w;
        As[ac + 0][ar + 64] = a1.x; As[ac + 1][ar + 64] = a1.y;
        As[ac + 2][ar + 64] = a1.z; As[ac + 3][ar + 64] = a1.w;
        *reinterpret_cast<float4*>(&Bs[br][bc])     = b0;
        *reinterpret_cast<float4*>(&Bs[br + 8][bc]) = b1;
        __syncthreads();
#pragma unroll
        for (int k = 0; k < 16; ++k) {
            float4 xa0 = *reinterpret_cast<const float4*>(&As[k][ty << 2]);
            float4 xa1 = *reinterpret_cast<const float4*>(&As[k][(ty << 2) + 64]);
            float4 xb0 = *reinterpret_cast<const float4*>(&Bs[k][tx << 2]);
            float4 xb1 = *reinterpret_cast<const float4*>(&Bs[k][(tx << 2) + 64]);
            float av[8] = {xa0.x, xa0.y, xa0.z, xa0.w, xa1.x, xa1.y, xa1.z, xa1.w};
            float bv[8] = {xb0.x, xb0.y, xb0.z, xb0.w, xb1.x, xb1.y, xb1.z, xb1.w};
#pragma unroll
            for (int i = 0; i < 8; ++i)
#pragma unroll
                for (int j = 0; j < 8; ++j)
                    acc[i][j] = fmaf(av[i], bv[j], acc[i][j]);
        }
    }
#pragma unroll
    for (int i = 0; i < 8; ++i) {
        int r = row0 + (ty << 2) + (i & 3) + ((i & 4) << 4);
        float* Crow = C + (size_t)r * N;
#pragma unroll
        for (int jh = 0; jh < 2; ++jh) {
            int cc = col0 + (tx << 2) + (jh << 6);
            float4 v;
            v.x = acc[i][jh * 4 + 0] + bias[cc + 0];
            v.y = acc[i][jh * 4 + 1] + bias[cc + 1];
            v.z = acc[i][jh * 4 + 2] + bias[cc + 2];
            v.w = acc[i][jh * 4 + 3] + bias[cc + 3];
            *reinterpret_cast<float4*>(Crow + cc) = v;
        }
    }
}

// ---------------------------------------------------------------------------
// Sim + argmax via 6-product i8x3 fixed-point MFMA (mfma_i32_16x16x64_i8).
// Monotone integer key: key = (((A1<<8)+A2)<<2) + (A3>>6). Same product set
// and error bound as the verified round-3 kernel; MFMA order identical.
// DOUBLE-BUFFERED emb staging (2 x 24576 B, 2 blocks/CU at 102 KB).
// Per c-iter: [stage next chunk -> other buf][compute cur][syncthreads].
// Race audit: compute(c) reads buf[c&1], staged in iter c-1 and fenced by
// iter c-1's trailing __syncthreads (vmcnt(0)+barrier); stage(c+1) writes
// buf[(c+1)&1], whose last readers (compute(c-1)) are fenced by the same
// barrier. Plain __syncthreads only.
// ---------------------------------------------------------------------------
#define EPL8 8192   // bytes per 128x64 i8 plane tile
__global__ __launch_bounds__(256, 2) void argmax_mfma(
        const s8* __restrict__ Z0, const s8* __restrict__ Z1, const s8* __restrict__ Z2,
        const s8* __restrict__ E0, const s8* __restrict__ E1, const s8* __restrict__ E2,
        float* __restrict__ pval, int* __restrict__ pidx) {
    __shared__ __align__(16) s8 Bsh[2][3 * EPL8];   // 49152 B double-buffered
    __shared__ int sk[128][2];
    __shared__ int si[128][2];
    const int rb = blockIdx.x, split = blockIdx.y;
    const int row0 = rb * 128, cbase = split * 1024;
    const int t = threadIdx.x;
    const int w = t >> 6, lane = t & 63, lm = lane & 15, q = lane >> 4;
    const int wr = (w >> 1) * 64, wc = (w & 1) * 64;

    // staging geometry: each wave-instruction covers 16 rows x 4 chunks(16B)
    const int sr  = lane >> 2;        // row within 16-row group
    const int scc = lane & 3;         // LDS chunk slot

    // Resident A fragments: [plane][mtile], 16 contiguous k-bytes per lane
    i32x4 a[3][4];
#pragma unroll
    for (int i = 0; i < 4; ++i) {
        int row = row0 + wr + i * 16 + lm;
        size_t off = (size_t)row * 64 + q * 16;
        a[0][i] = *reinterpret_cast<const i32x4*>(Z0 + off);
        a[1][i] = *reinterpret_cast<const i32x4*>(Z1 + off);
        a[2][i] = *reinterpret_cast<const i32x4*>(Z2 + off);
    }

    // prologue: stage chunk 0 -> buf 0
#pragma unroll
    for (int p = 0; p < 3; ++p) {
        const s8* Ep = (p == 0) ? E0 : ((p == 1) ? E1 : E2);
#pragma unroll
        for (int rr = 0; rr < 2; ++rr) {
            int g = rr * 4 + w;            // 16-row group 0..7
            int r = g * 16 + sr;           // local code row 0..127
            int cg = scc ^ (r & 3);        // swizzled source chunk
            gll16(Ep + (size_t)(cbase + r) * 64 + cg * 16,
                  &Bsh[0][p * EPL8 + g * 1024 + lane * 16]);
        }
    }
    __syncthreads();

    int bkey[4][4];
    int bidx[4][4];
#pragma unroll
    for (int i = 0; i < 4; ++i)
#pragma unroll
        for (int r = 0; r < 4; ++r) { bkey[i][r] = (int)0x80000000; bidx[i][r] = 0; }

    for (int c = 0; c < 8; ++c) {
        // stage next chunk into the other buffer (loads fly under compute)
        if (c < 7) {
            const int code0n = cbase + (c + 1) * 128;
            s8* dst = &Bsh[(c + 1) & 1][0];
#pragma unroll
            for (int p = 0; p < 3; ++p) {
                const s8* Ep = (p == 0) ? E0 : ((p == 1) ? E1 : E2);
#pragma unroll
                for (int rr = 0; rr < 2; ++rr) {
                    int g = rr * 4 + w;
                    int r = g * 16 + sr;
                    int cg = scc ^ (r & 3);
                    gll16(Ep + (size_t)(code0n + r) * 64 + cg * 16,
                          dst + p * EPL8 + g * 1024 + lane * 16);
                }
            }
        }
        // compute current chunk
        const s8* Bc = &Bsh[c & 1][0];
        const int code0 = cbase + c * 128;
#pragma unroll
        for (int j = 0; j < 4; ++j) {
            int rl = wc + j * 16 + lm;
            int nb = rl * 64;
            int sidx = (q ^ (rl & 3)) * 16;
            i32x4 bh = *reinterpret_cast<const i32x4*>(&Bc[0 * EPL8 + nb + sidx]);
            i32x4 bm = *reinterpret_cast<const i32x4*>(&Bc[1 * EPL8 + nb + sidx]);
            i32x4 bl = *reinterpret_cast<const i32x4*>(&Bc[2 * EPL8 + nb + sidx]);
            int code = code0 + rl;
#pragma unroll
            for (int i = 0; i < 4; ++i) {
                i32x4 A1 = (i32x4){0, 0, 0, 0};
                i32x4 A2 = (i32x4){0, 0, 0, 0};
                i32x4 A3 = (i32x4){0, 0, 0, 0};
                A1 = __builtin_amdgcn_mfma_i32_16x16x64_i8(a[0][i], bh, A1, 0, 0, 0);
                A2 = __builtin_amdgcn_mfma_i32_16x16x64_i8(a[0][i], bm, A2, 0, 0, 0);
                A2 = __builtin_amdgcn_mfma_i32_16x16x64_i8(a[1][i], bh, A2, 0, 0, 0);
                A3 = __builtin_amdgcn_mfma_i32_16x16x64_i8(a[0][i], bl, A3, 0, 0, 0);
                A3 = __builtin_amdgcn_mfma_i32_16x16x64_i8(a[2][i], bh, A3, 0, 0, 0);
                A3 = __builtin_amdgcn_mfma_i32_16x16x64_i8(a[1][i], bm, A3, 0, 0, 0);
#pragma unroll
                for (int r = 0; r < 4; ++r) {
                    // monotone int key: ((A1<<8)+A2)<<2 + (A3>>6)
                    int key = ((((A1[r] << 8) + A2[r]) << 2) + (A3[r] >> 6));
                    if (key > bkey[i][r]) { bkey[i][r] = key; bidx[i][r] = code; }
                }
            }
        }
        __syncthreads();   // next chunk landed + all waves done reading buf[c&1]
    }
    // reduce over the 16 lanes sharing each row (lm bits 0..3), stash winner
#pragma unroll
    for (int i = 0; i < 4; ++i)
#pragma unroll
        for (int r = 0; r < 4; ++r) {
            int v  = bkey[i][r];
            int id = bidx[i][r];
#pragma unroll
            for (int msk = 1; msk <= 8; msk <<= 1) {
                int ov  = __shfl_xor(v, msk, 64);
                int oid = __shfl_xor(id, msk, 64);
                if (ov > v || (ov == v && oid < id)) { v = ov; id = oid; }
            }
            if (lm == 0) {
                int rl = wr + i * 16 + q * 4 + r;
                sk[rl][w & 1] = v;
                si[rl][w & 1] = id;
            }
        }
    __syncthreads();
    if (t < 128) {
        int v0 = sk[t][0], v1 = sk[t][1];
        int i0 = si[t][0], i1 = si[t][1];
        int bv, bi;
        if (v1 > v0 || (v1 == v0 && i1 < i0)) { bv = v1; bi = i1; }
        else                                  { bv = v0; bi = i0; }
        pval[(size_t)(row0 + t) * 8 + split] = (float)bv;   // unused downstream
        pidx[(size_t)(row0 + t) * 8 + split] = bi;
    }
}

// ---------------------------------------------------------------------------
// Exact fp32 rescore of the 8 split candidates per row -> final idx.
// Fused commitment loss: ||emb[idx]-Zn||^2 = 2 - 2*sim (unit vectors).
// ---------------------------------------------------------------------------
__global__ __launch_bounds__(256) void merge_rescore(const float* __restrict__ Zn,
                                                     const float* __restrict__ emb,
                                                     const int* __restrict__ pidx,
                                                     int* __restrict__ idx,
                                                     float* __restrict__ loss) {
    __shared__ float sv[4][8];
    __shared__ int   si[4][8];
    const int t = threadIdx.x;
    const int w = t >> 6, lane = t & 63;
    const int row = blockIdx.x * 4 + w;
    const int cg = lane >> 3, s = lane & 7;
    int cand = pidx[(size_t)row * 8 + cg];
    const float4* zp = reinterpret_cast<const float4*>(Zn + (size_t)row * 64 + s * 8);
    const float4* ep = reinterpret_cast<const float4*>(emb + (size_t)cand * 64 + s * 8);
    float4 z0 = zp[0], z1 = zp[1], e0 = ep[0], e1 = ep[1];
    float acc = z0.x * e0.x + z0.y * e0.y + z0.z * e0.z + z0.w * e0.w
              + z1.x * e1.x + z1.y * e1.y + z1.z * e1.z + z1.w * e1.w;
#pragma unroll
    for (int msk = 1; msk <= 4; msk <<= 1) acc += __shfl_xor(acc, msk, 64);
    if (s == 0) { sv[w][cg] = acc; si[w][cg] = cand; }
    __syncthreads();
    if (lane == 0) {
        float bv = sv[w][0];
        int   bi = si[w][0];
#pragma unroll
        for (int cc = 1; cc < 8; ++cc) {
            float v = sv[w][cc];
            int   ii = si[w][cc];
            if (v > bv || (v == bv && ii < bi)) { bv = v; bi = ii; }
        }
        idx[row] = bi;
        // commitment loss: ||e - z||^2 = 2 - 2*<e,z> for unit vectors
        atomicAdd(loss, (2.0f - 2.0f * bv) * (1.0f / (16384.0f * 64.0f)));
    }
}

// out[n,:] = P[idx[n],:]  — MUST complete before onehot_k (P lives inside the
// codex scratch region; fusing these races across blocks — round-5 failure).
__global__ __launch_bounds__(192) void gather_k(const int* __restrict__ idx,
                                                const float* __restrict__ P,
                                                float* __restrict__ out) {
    const int r = blockIdx.x;
    const int t = threadIdx.x;
    const int k = idx[r];
    float4 v = *reinterpret_cast<const float4*>(&P[(size_t)k * 768 + t * 4]);
    *reinterpret_cast<float4*>(&out[(size_t)r * 768 + t * 4]) = v;
}

// codex_probs: write the full one-hot matrix in one streaming pass.
__global__ __launch_bounds__(256) void onehot_k(const int* __restrict__ idx,
                                                float* __restrict__ codex) {
    const int row = blockIdx.x;
    const int k = idx[row];
    float* base = codex + (size_t)row * 8192;
#pragma unroll
    for (int it = 0; it < 8; ++it) {
        int col = it * 1024 + threadIdx.x * 4;
        float4 v = {0.f, 0.f, 0.f, 0.f};
        unsigned d = (unsigned)(k - col);
        if (d < 4u) (&v.x)[d] = 1.0f;
        *reinterpret_cast<float4*>(base + col) = v;
    }
}

// ---------------------------------------------------------------------------
extern "C" void kernel_launch(void* const* d_in, const int* in_sizes, int n_in,
                              void* d_out, int out_size, void* d_ws, size_t ws_size,
                              hipStream_t stream) {
    const float* Z     = (const float*)d_in[0];
    const float* W1    = (const float*)d_in[1];
    const float* b1    = (const float*)d_in[2];
    const float* W2    = (const float*)d_in[3];
    const float* b2    = (const float*)d_in[4];
    const float* emb   = (const float*)d_in[5];
    const float* gamma = (const float*)d_in[6];
    const float* beta  = (const float*)d_in[7];
    const float* Wp    = (const float*)d_in[8];
    const float* bp    = (const float*)d_in[9];

    float* outF  = (float*)d_out;
    float* H     = outF + H_OFF;
    float* P     = outF + P_OFF;
    float* Zn    = outF + ZN_OFF;
    float* Q     = outF + Q_OFF;
    u16*   ZH    = (u16*)(outF + ZH_OFF);
    u16*   ZM    = (u16*)(outF + ZM_OFF);
    u16*   ZL    = (u16*)(outF + ZL_OFF);
    u16*   W1H   = (u16*)(outF + W1H_OFF);
    u16*   W1M   = (u16*)(outF + W1M_OFF);
    u16*   W1L   = (u16*)(outF + W1L_OFF);
    s8*    Z0    = (s8*)(outF + NH_OFF);
    s8*    Z1p   = (s8*)(outF + NM_OFF);
    s8*    Z2p   = (s8*)(outF + NL_OFF);
    s8*    E0    = (s8*)(outF + EH_OFF);
    s8*    E1    = (s8*)(outF + EM_OFF);
    s8*    E2    = (s8*)(outF + EL_OFF);
    float* lossp = outF + OUT_LOSS;
    float* codex = outF + OUT_CODEX;

    float* pval = (float*)d_ws;                       // 16384*8 floats
    int*   pidx = (int*)((char*)d_ws + 524288);       // 16384*8 ints
    int*   idxp = (int*)((char*)d_ws + 1048576);      // 16384 ints

    // fused preprocessing (split_z + split_w1t + qln_emb + loss zeroing)
    prep_k<<<8768, 256, 0, stream>>>(Z, ZH, ZM, ZL, W1, W1H, W1M, W1L,
                                     emb, gamma, beta, E0, E1, E2, Q, lossp);
    // H = tanh(Z @ W1 + b1)   (MFMA bf16x3, BN=192 -> 512 blocks, no tail)
    gemm1_mfma<<<512, 256, 0, stream>>>(ZH, ZM, ZL, W1H, W1M, W1L, b1, H);
    // Zn = l2norm(H @ W2 + b2) + i8x3 fixed-point planes
    gemm2_l2<<<256, 256, 0, stream>>>(H, W2, b2, Zn, Z0, Z1p, Z2p);
    // P = Q @ Wp + bp  (gathered later)
    gemm128<<<dim3(6, 64), 256, 0, stream>>>(Q, Wp, bp, P, KCODES, DMODEL, DCODE);
    // sim + per-split argmax (i8 MFMA, double-buffered emb staging)
    argmax_mfma<<<dim3(128, 8), 256, 0, stream>>>(Z0, Z1p, Z2p, E0, E1, E2, pval, pidx);
    // exact fp32 rescore of 8 candidates -> idx (+ fused commitment loss)
    merge_rescore<<<4096, 256, 0, stream>>>(Zn, emb, pidx, idxp, lossp);
    // out[n] = P[idx[n]]  (must COMPLETE before onehot_k overwrites scratch)
    gather_k<<<16384, 192, 0, stream>>>(idxp, P, outF);
    // codex one-hot (also wipes scratch region deterministically)
    onehot_k<<<16384, 256, 0, stream>>>(idxp, codex);
}

// Round 10
// 1099.294 us; speedup vs baseline: 1.0170x; 1.0170x over previous
//
#include <hip/hip_runtime.h>
#include <cstddef>
#include <cstdint>

typedef unsigned short u16;
typedef signed char s8;
typedef short bf16x8 __attribute__((ext_vector_type(8)));
typedef float f32x4 __attribute__((ext_vector_type(4)));
typedef int i32x4 __attribute__((ext_vector_type(4)));

// Problem constants (B=16, S=1024, D=768, DC=64, K=8192)
#define NROW   16384
#define DMODEL 768
#define DCODE  64
#define KCODES 8192

// d_out layout (float element offsets): [out 16384*768][loss 1][codex 16384*8192]
#define OUT_LOSS  12582912
#define OUT_CODEX 12582913
// 16B-aligned scratch carved out of the codex region (fully overwritten by the
// one-hot writer at the end). All offsets in float units, multiples of 4.
// *** ORDERING INVARIANT: anything stored here (esp. P) must be fully consumed
// *** by dispatches that COMPLETE before onehot_k launches. Fusing a consumer
// *** of P with the one-hot writer races across blocks (round-5 failure).
#define S0        12582916
#define H_OFF     (S0)                        // 12582912 f
#define P_OFF     (H_OFF + 12582912)          // 6291456 f
#define ZN_OFF    (P_OFF + 6291456)           // 1048576 f
#define Q_OFF     (ZN_OFF + 1048576)          // 524288 f
#define ZH_OFF    (Q_OFF + 524288)            // u16 planes of Z: each 12582912 u16 = 6291456 f
#define ZM_OFF    (ZH_OFF + 6291456)
#define ZL_OFF    (ZM_OFF + 6291456)
#define W1H_OFF   (ZL_OFF + 6291456)          // W1^T planes: each 589824 u16 = 294912 f
#define W1M_OFF   (W1H_OFF + 294912)
#define W1L_OFF   (W1M_OFF + 294912)
#define NH_OFF    (W1L_OFF + 294912)          // Zn i8 planes: each 1048576 B (region sized for 2x)
#define NM_OFF    (NH_OFF + 524288)
#define NL_OFF    (NM_OFF + 524288)
#define EH_OFF    (NL_OFF + 524288)           // emb i8 planes: each 524288 B (region sized for 2x)
#define EM_OFF    (EH_OFF + 262144)
#define EL_OFF    (EM_OFF + 262144)

__device__ __forceinline__ u16 f2bf(float x) {
    unsigned u = __float_as_uint(x);
    u += 0x7fffu + ((u >> 16) & 1u);          // RTNE
    return (u16)(u >> 16);
}
__device__ __forceinline__ float bf2f(u16 h) {
    return __uint_as_float(((unsigned)h) << 16);
}

// Exact 24-bit fixed-point split (scale 2^22, |x|<=1): x_q = h*2^16 + m*2^8 + l
__device__ __forceinline__ void f2i8x3(float x, int& h, int& m, int& l) {
    int q = (int)rintf(x * 4194304.0f);       // 2^22
    l = (q << 24) >> 24;
    int t = (q - l) >> 8;
    m = (t << 24) >> 24;
    h = (t - m) >> 8;                         // |h| <= 64
}

// async global->LDS, 16 B per lane. LDS dest is wave-uniform base + lane*16
// (m104/m108): callers must pass lds = base + lane*16 exactly.
typedef __attribute__((address_space(1))) const unsigned int gas_u32;
typedef __attribute__((address_space(3))) unsigned int las_u32;
__device__ __forceinline__ void gll16(const void* g, void* l) {
    __builtin_amdgcn_global_load_lds((gas_u32*)g, (las_u32*)l, 16, 0, 0);
}

// ---------------------------------------------------------------------------
// Fused preprocessing (one launch, block-range partitioned):
//   blocks [0, 6144)      : split Z -> 3 bf16 planes
//   blocks [6144, 6720)   : split+transpose W1 -> 3 bf16 planes (24x24 tiles)
//   blocks [6720, 8768)   : emb -> i8x3 planes + Q = LN(emb)*gamma+beta
// Block 6144 thread 0 also zeroes the loss accumulator (replaces memset).
// ---------------------------------------------------------------------------
__global__ __launch_bounds__(256) void prep_k(
        const float* __restrict__ Z,
        u16* __restrict__ Ph, u16* __restrict__ Pm, u16* __restrict__ Pl,
        const float* __restrict__ W1,
        u16* __restrict__ Th, u16* __restrict__ Tm, u16* __restrict__ Tl,
        const float* __restrict__ emb,
        const float* __restrict__ gamma, const float* __restrict__ beta,
        s8* __restrict__ E0, s8* __restrict__ E1, s8* __restrict__ E2,
        float* __restrict__ Q, float* __restrict__ loss) {
    __shared__ float tile[32][33];
    const int b = blockIdx.x;
    const int t = threadIdx.x;

    if (b < 6144) {
        // ---- split_z ----
        const size_t g = (size_t)b * 256 + t;   // x8 elements
        const float4* zp = reinterpret_cast<const float4*>(Z) + g * 2;
        float4 a = zp[0], bb = zp[1];
        float xs[8] = {a.x, a.y, a.z, a.w, bb.x, bb.y, bb.z, bb.w};
        union { u16 u[8]; uint4 v; } ph, pm, pl;
#pragma unroll
        for (int k = 0; k < 8; ++k) {
            float x = xs[k];
            u16 h = f2bf(x); float r = x - bf2f(h);
            u16 m = f2bf(r); float r2 = r - bf2f(m);
            u16 l = f2bf(r2);
            ph.u[k] = h; pm.u[k] = m; pl.u[k] = l;
        }
        *reinterpret_cast<uint4*>(Ph + g * 8) = ph.v;
        *reinterpret_cast<uint4*>(Pm + g * 8) = pm.v;
        *reinterpret_cast<uint4*>(Pl + g * 8) = pl.v;
    } else if (b < 6720) {
        // ---- split_w1t ----
        if (b == 6144 && t == 0) *loss = 0.0f;
        const int bb = b - 6144;
        const int k0 = (bb / 24) * 32, n0 = (bb % 24) * 32;
        const int tc = t & 31, tr = t >> 5;          // tr 0..7
#pragma unroll
        for (int rr = 0; rr < 4; ++rr) {
            int r = tr * 4 + rr;
            tile[r][tc] = W1[(size_t)(k0 + r) * 768 + n0 + tc];
        }
        __syncthreads();
#pragma unroll
        for (int rr = 0; rr < 4; ++rr) {
            int n = n0 + tr * 4 + rr;
            int k = k0 + tc;
            float x = tile[tc][tr * 4 + rr];
            u16 h = f2bf(x); float r = x - bf2f(h);
            u16 m = f2bf(r); u16 l = f2bf(r - bf2f(m));
            Th[(size_t)n * 768 + k] = h;
            Tm[(size_t)n * 768 + k] = m;
            Tl[(size_t)n * 768 + k] = l;
        }
    } else {
        // ---- qln_emb ----
        const int bb = b - 6720;
        const int lane = t & 63;
        const int n = bb * 4 + (t >> 6);
        float x = emb[(size_t)n * 64 + lane];
        int h8, m8, l8;
        f2i8x3(x, h8, m8, l8);
        E0[(size_t)n * 64 + lane] = (s8)h8;
        E1[(size_t)n * 64 + lane] = (s8)m8;
        E2[(size_t)n * 64 + lane] = (s8)l8;
        float mu = x;
#pragma unroll
        for (int off = 32; off > 0; off >>= 1) mu += __shfl_xor(mu, off, 64);
        mu *= (1.0f / 64.0f);
        float d = x - mu;
        float var = d * d;
#pragma unroll
        for (int off = 32; off > 0; off >>= 1) var += __shfl_xor(var, off, 64);
        var *= (1.0f / 64.0f);
        Q[(size_t)n * 64 + lane] = d * rsqrtf(var + 1e-5f) * gamma[lane] + beta[lane];
    }
}

// ---------------------------------------------------------------------------
// GEMM1 via 6-product bf16x3 MFMA: H = tanh(Z @ W1 + b1).
// M=16384, N=768, K=768. BM=128, BN=192, BK=32. 512 blocks = 2/CU, no tail.
// Per-element accumulation order fixed -> bitwise-stable H across rounds.
// ---------------------------------------------------------------------------
#define APL 4096    // u16 per 128x32 A plane tile
#define BPL 6144    // u16 per 192x32 B plane tile
#define BOFF (3 * APL)
__global__ __launch_bounds__(256, 2) void gemm1_mfma(
        const u16* __restrict__ Ah0, const u16* __restrict__ Am0, const u16* __restrict__ Al0,
        const u16* __restrict__ Bh0, const u16* __restrict__ Bm0, const u16* __restrict__ Bl0,
        const float* __restrict__ bias, float* __restrict__ H) {
    __shared__ u16 lds[3 * APL + 3 * BPL];    // A planes then B planes (61440 B)

    // 512 blocks: xcd = b&7, ii = b>>3 (0..63). Each XCD: 16 row-tiles x 4 col-tiles.
    const int b = blockIdx.x;
    const int xcd = b & 7, ii = b >> 3;
    const int row0 = (xcd * 16 + (ii & 15)) * 128;
    const int col0 = (ii >> 4) * 192;

    const int t = threadIdx.x;
    const int w = t >> 6, lane = t & 63, lm = lane & 15, q = lane >> 4;
    const int wr = (w >> 1) * 64, wc = (w & 1) * 96;

    const u16* Ap[3] = {Ah0, Am0, Al0};
    const u16* Bp[3] = {Bh0, Bm0, Bl0};

    // staging geometry: each wave-instruction covers 16 rows x 4 chunks(16B)
    const int sr  = lane >> 2;        // row within 16-row group
    const int scc = lane & 3;         // LDS chunk slot

    f32x4 acc[4][6];
#pragma unroll
    for (int i = 0; i < 4; ++i)
#pragma unroll
        for (int j = 0; j < 6; ++j) acc[i][j] = (f32x4){0.f, 0.f, 0.f, 0.f};

    for (int k0 = 0; k0 < 768; k0 += 32) {
        __syncthreads();
#pragma unroll
        for (int p = 0; p < 3; ++p) {
#pragma unroll
            for (int rr = 0; rr < 2; ++rr) {      // A: 8 groups of 16 rows
                int g = rr * 4 + w;
                int r = g * 16 + sr;              // local row 0..127
                int cg = scc ^ ((r >> 1) & 3);    // swizzled source chunk
                gll16(Ap[p] + (size_t)(row0 + r) * 768 + k0 + cg * 8,
                      &lds[p * APL + g * 512 + lane * 8]);
            }
#pragma unroll
            for (int rr = 0; rr < 3; ++rr) {      // B: 12 groups of 16 rows
                int g = rr * 4 + w;
                int r = g * 16 + sr;              // local row 0..191
                int cg = scc ^ ((r >> 1) & 3);
                gll16(Bp[p] + (size_t)(col0 + r) * 768 + k0 + cg * 8,
                      &lds[BOFF + p * BPL + g * 512 + lane * 8]);
            }
        }
        __syncthreads();

        bf16x8 fah[4], fam[4], fal[4];
#pragma unroll
        for (int i = 0; i < 4; ++i) {
            int r = wr + i * 16 + lm;
            int off = r * 32 + ((q ^ ((r >> 1) & 3)) * 8);
            fah[i] = *reinterpret_cast<const bf16x8*>(&lds[0 * APL + off]);
            fam[i] = *reinterpret_cast<const bf16x8*>(&lds[1 * APL + off]);
            fal[i] = *reinterpret_cast<const bf16x8*>(&lds[2 * APL + off]);
        }
#pragma unroll
        for (int j = 0; j < 6; ++j) {
            int rb = wc + j * 16 + lm;            // 0..191
            int offb = rb * 32 + ((q ^ ((rb >> 1) & 3)) * 8);
            bf16x8 fbh = *reinterpret_cast<const bf16x8*>(&lds[BOFF + 0 * BPL + offb]);
            bf16x8 fbm = *reinterpret_cast<const bf16x8*>(&lds[BOFF + 1 * BPL + offb]);
            bf16x8 fbl = *reinterpret_cast<const bf16x8*>(&lds[BOFF + 2 * BPL + offb]);
#pragma unroll
            for (int i = 0; i < 4; ++i) {
                f32x4 c = acc[i][j];
                c = __builtin_amdgcn_mfma_f32_16x16x32_bf16(fah[i], fbl, c, 0, 0, 0);
                c = __builtin_amdgcn_mfma_f32_16x16x32_bf16(fal[i], fbh, c, 0, 0, 0);
                c = __builtin_amdgcn_mfma_f32_16x16x32_bf16(fam[i], fbm, c, 0, 0, 0);
                c = __builtin_amdgcn_mfma_f32_16x16x32_bf16(fah[i], fbm, c, 0, 0, 0);
                c = __builtin_amdgcn_mfma_f32_16x16x32_bf16(fam[i], fbh, c, 0, 0, 0);
                c = __builtin_amdgcn_mfma_f32_16x16x32_bf16(fah[i], fbh, c, 0, 0, 0);
                acc[i][j] = c;
            }
        }
    }
    // epilogue: +bias, tanh, store
#pragma unroll
    for (int i = 0; i < 4; ++i)
#pragma unroll
        for (int j = 0; j < 6; ++j) {
            int col = col0 + wc + j * 16 + lm;
            float bv = bias[col];
#pragma unroll
            for (int r = 0; r < 4; ++r) {
                int row = row0 + wr + i * 16 + q * 4 + r;
                H[(size_t)row * 768 + col] = tanhf(acc[i][j][r] + bv);
            }
        }
}

// ---------------------------------------------------------------------------
// Fused mid-stage (one launch; the two parts are data-independent):
//   blocks [0,256)   : gemm2_l2 — Zn = l2norm(H @ W2 + b2) + i8x3 planes
//   blocks [256,640) : gemm128  — P = Q @ Wp + bp  (8192x768, K=64)
// gemm2 alone ran 256 blocks = 1 block/CU (half the slots idle); gemm128's
// 384 blocks now fill the gap instead of running serialized afterwards.
// Shared memory: one 16 KB pool carved per branch (branch uniform per block).
// Per-branch code byte-identical to the round-6 kernels.
// ---------------------------------------------------------------------------
__global__ __launch_bounds__(256) void mid_k(
        const float* __restrict__ H, const float* __restrict__ W2,
        const float* __restrict__ b2, float* __restrict__ Zn,
        s8* __restrict__ Z0, s8* __restrict__ Z1, s8* __restrict__ Z2,
        const float* __restrict__ Q, const float* __restrict__ Wp,
        const float* __restrict__ bp, float* __restrict__ P) {
    __shared__ float smem[4096];              // 16 KB
    const int t = threadIdx.x;

    if (blockIdx.x < 256) {
        // ---- gemm2_l2 ----
        float (*As)[64] = reinterpret_cast<float(*)[64]>(smem);
        float (*Bs)[64] = reinterpret_cast<float(*)[64]>(smem + 1024);
        const int row0 = blockIdx.x * 64;
        const int tx = t & 15, ty = t >> 4;
        const int ar = t >> 2, ac = (t & 3) << 2;
        const int br = t >> 4, bc = (t & 15) << 2;

        const float* Ap = H + (size_t)(row0 + ar) * 768 + ac;
        const float* Bp = W2 + (size_t)br * 64 + bc;

        float acc[4][4];
#pragma unroll
        for (int i = 0; i < 4; ++i)
#pragma unroll
            for (int j = 0; j < 4; ++j) acc[i][j] = 0.0f;

        for (int k0 = 0; k0 < 768; k0 += 16) {
            float4 a0 = *reinterpret_cast<const float4*>(Ap + k0);
            float4 b0 = *reinterpret_cast<const float4*>(Bp + (size_t)k0 * 64);
            __syncthreads();
            As[ac + 0][ar] = a0.x; As[ac + 1][ar] = a0.y;
            As[ac + 2][ar] = a0.z; As[ac + 3][ar] = a0.w;
            *reinterpret_cast<float4*>(&Bs[br][bc]) = b0;
            __syncthreads();
#pragma unroll
            for (int k = 0; k < 16; ++k) {
                float4 xa = *reinterpret_cast<const float4*>(&As[k][ty << 2]);
                float4 xb = *reinterpret_cast<const float4*>(&Bs[k][tx << 2]);
                float av[4] = {xa.x, xa.y, xa.z, xa.w};
                float bv[4] = {xb.x, xb.y, xb.z, xb.w};
#pragma unroll
                for (int i = 0; i < 4; ++i)
#pragma unroll
                    for (int j = 0; j < 4; ++j)
                        acc[i][j] = fmaf(av[i], bv[j], acc[i][j]);
            }
        }
        const int c = tx << 2;
        const float4 bv4 = *reinterpret_cast<const float4*>(b2 + c);
#pragma unroll
        for (int i = 0; i < 4; ++i) {
            float v0 = acc[i][0] + bv4.x;
            float v1 = acc[i][1] + bv4.y;
            float v2 = acc[i][2] + bv4.z;
            float v3 = acc[i][3] + bv4.w;
            float ss = v0 * v0 + v1 * v1 + v2 * v2 + v3 * v3;
#pragma unroll
            for (int msk = 1; msk <= 8; msk <<= 1) ss += __shfl_xor(ss, msk, 64);
            float sc = 1.0f / fmaxf(sqrtf(ss), 1e-12f);
            v0 *= sc; v1 *= sc; v2 *= sc; v3 *= sc;
            int r = row0 + (ty << 2) + i;
            float4 z = {v0, v1, v2, v3};
            *reinterpret_cast<float4*>(Zn + (size_t)r * 64 + c) = z;
            float vs[4] = {v0, v1, v2, v3};
            unsigned pk0 = 0, pk1 = 0, pk2 = 0;
#pragma unroll
            for (int j = 0; j < 4; ++j) {
                int h8, m8, l8;
                f2i8x3(vs[j], h8, m8, l8);
                pk0 |= ((unsigned)(unsigned char)(s8)h8) << (8 * j);
                pk1 |= ((unsigned)(unsigned char)(s8)m8) << (8 * j);
                pk2 |= ((unsigned)(unsigned char)(s8)l8) << (8 * j);
            }
            *reinterpret_cast<unsigned*>(Z0 + (size_t)r * 64 + c) = pk0;
            *reinterpret_cast<unsigned*>(Z1 + (size_t)r * 64 + c) = pk1;
            *reinterpret_cast<unsigned*>(Z2 + (size_t)r * 64 + c) = pk2;
        }
    } else {
        // ---- gemm128: P = Q @ Wp + bp, M=8192, N=768, K=64 ----
        float (*As)[128] = reinterpret_cast<float(*)[128]>(smem);
        float (*Bs)[128] = reinterpret_cast<float(*)[128]>(smem + 2048);
        const int bb = blockIdx.x - 256;      // 0..383
        const int row0 = (bb / 6) * 128;
        const int col0 = (bb % 6) * 128;
        const int N = DMODEL, K = DCODE;
        const int tx = t & 15, ty = t >> 4;
        const int ar = t >> 2, ac = (t & 3) << 2;
        const int br = t >> 5, bc = (t & 31) << 2;

        const float* Ap0 = Q + (size_t)(row0 + ar) * K + ac;
        const float* Ap1 = Ap0 + (size_t)64 * K;
        const float* Bp0 = Wp + (size_t)br * N + col0 + bc;
        const float* Bp1 = Bp0 + (size_t)8 * N;

        float acc[8][8];
#pragma unroll
        for (int i = 0; i < 8; ++i)
#pragma unroll
            for (int j = 0; j < 8; ++j) acc[i][j] = 0.0f;

        for (int k0 = 0; k0 < K; k0 += 16) {
            float4 a0 = *reinterpret_cast<const float4*>(Ap0 + k0);
            float4 a1 = *reinterpret_cast<const float4*>(Ap1 + k0);
            float4 b0 = *reinterpret_cast<const float4*>(Bp0 + (size_t)k0 * N);
            float4 b1 = *reinterpret_cast<const float4*>(Bp1 + (size_t)k0 * N);
            __syncthreads();
            As[ac + 0][ar] = a0.x; As[ac + 1][ar] = a0.y;
            As[ac + 2][ar] = a0.z; As[ac + 3][ar] = a0.w;
            As[ac + 0][ar + 64] = a1.x; As[ac + 1][ar + 64] = a1.y;
            As[ac + 2][ar + 64] = a1.z; As[ac + 3][ar + 64] = a1.w;
            *reinterpret_cast<float4*>(&Bs[br][bc])     = b0;
            *reinterpret_cast<float4*>(&Bs[br + 8][bc]) = b1;
            __syncthreads();
#pragma unroll
            for (int k = 0; k < 16; ++k) {
                float4 xa0 = *reinterpret_cast<const float4*>(&As[k][ty << 2]);
                float4 xa1 = *reinterpret_cast<const float4*>(&As[k][(ty << 2) + 64]);
                float4 xb0 = *reinterpret_cast<const float4*>(&Bs[k][tx << 2]);
                float4 xb1 = *reinterpret_cast<const float4*>(&Bs[k][(tx << 2) + 64]);
                float av[8] = {xa0.x, xa0.y, xa0.z, xa0.w, xa1.x, xa1.y, xa1.z, xa1.w};
                float bv[8] = {xb0.x, xb0.y, xb0.z, xb0.w, xb1.x, xb1.y, xb1.z, xb1.w};
#pragma unroll
                for (int i = 0; i < 8; ++i)
#pragma unroll
                    for (int j = 0; j < 8; ++j)
                        acc[i][j] = fmaf(av[i], bv[j], acc[i][j]);
            }
        }
#pragma unroll
        for (int i = 0; i < 8; ++i) {
            int r = row0 + (ty << 2) + (i & 3) + ((i & 4) << 4);
            float* Crow = P + (size_t)r * N;
#pragma unroll
            for (int jh = 0; jh < 2; ++jh) {
                int cc = col0 + (tx << 2) + (jh << 6);
                float4 v;
                v.x = acc[i][jh * 4 + 0] + bp[cc + 0];
                v.y = acc[i][jh * 4 + 1] + bp[cc + 1];
                v.z = acc[i][jh * 4 + 2] + bp[cc + 2];
                v.w = acc[i][jh * 4 + 3] + bp[cc + 3];
                *reinterpret_cast<float4*>(Crow + cc) = v;
            }
        }
    }
}

// ---------------------------------------------------------------------------
// Sim + argmax via 6-product i8x3 fixed-point MFMA (mfma_i32_16x16x64_i8).
// Monotone integer key: key = (((A1<<8)+A2)<<2) + (A3>>6). Same product set
// and error bound as the verified round-3 kernel; MFMA order identical.
// DOUBLE-BUFFERED emb staging (2 x 24576 B, 2 blocks/CU at 102 KB).
// ---------------------------------------------------------------------------
#define EPL8 8192   // bytes per 128x64 i8 plane tile
__global__ __launch_bounds__(256, 2) void argmax_mfma(
        const s8* __restrict__ Z0, const s8* __restrict__ Z1, const s8* __restrict__ Z2,
        const s8* __restrict__ E0, const s8* __restrict__ E1, const s8* __restrict__ E2,
        float* __restrict__ pval, int* __restrict__ pidx) {
    __shared__ __align__(16) s8 Bsh[2][3 * EPL8];   // 49152 B double-buffered
    __shared__ int sk[128][2];
    __shared__ int si[128][2];
    const int rb = blockIdx.x, split = blockIdx.y;
    const int row0 = rb * 128, cbase = split * 1024;
    const int t = threadIdx.x;
    const int w = t >> 6, lane = t & 63, lm = lane & 15, q = lane >> 4;
    const int wr = (w >> 1) * 64, wc = (w & 1) * 64;

    // staging geometry: each wave-instruction covers 16 rows x 4 chunks(16B)
    const int sr  = lane >> 2;        // row within 16-row group
    const int scc = lane & 3;         // LDS chunk slot

    // Resident A fragments: [plane][mtile], 16 contiguous k-bytes per lane
    i32x4 a[3][4];
#pragma unroll
    for (int i = 0; i < 4; ++i) {
        int row = row0 + wr + i * 16 + lm;
        size_t off = (size_t)row * 64 + q * 16;
        a[0][i] = *reinterpret_cast<const i32x4*>(Z0 + off);
        a[1][i] = *reinterpret_cast<const i32x4*>(Z1 + off);
        a[2][i] = *reinterpret_cast<const i32x4*>(Z2 + off);
    }

    // prologue: stage chunk 0 -> buf 0
#pragma unroll
    for (int p = 0; p < 3; ++p) {
        const s8* Ep = (p == 0) ? E0 : ((p == 1) ? E1 : E2);
#pragma unroll
        for (int rr = 0; rr < 2; ++rr) {
            int g = rr * 4 + w;            // 16-row group 0..7
            int r = g * 16 + sr;           // local code row 0..127
            int cg = scc ^ (r & 3);        // swizzled source chunk
            gll16(Ep + (size_t)(cbase + r) * 64 + cg * 16,
                  &Bsh[0][p * EPL8 + g * 1024 + lane * 16]);
        }
    }
    __syncthreads();

    int bkey[4][4];
    int bidx[4][4];
#pragma unroll
    for (int i = 0; i < 4; ++i)
#pragma unroll
        for (int r = 0; r < 4; ++r) { bkey[i][r] = (int)0x80000000; bidx[i][r] = 0; }

    for (int c = 0; c < 8; ++c) {
        // stage next chunk into the other buffer (loads fly under compute)
        if (c < 7) {
            const int code0n = cbase + (c + 1) * 128;
            s8* dst = &Bsh[(c + 1) & 1][0];
#pragma unroll
            for (int p = 0; p < 3; ++p) {
                const s8* Ep = (p == 0) ? E0 : ((p == 1) ? E1 : E2);
#pragma unroll
                for (int rr = 0; rr < 2; ++rr) {
                    int g = rr * 4 + w;
                    int r = g * 16 + sr;
                    int cg = scc ^ (r & 3);
                    gll16(Ep + (size_t)(code0n + r) * 64 + cg * 16,
                          dst + p * EPL8 + g * 1024 + lane * 16);
                }
            }
        }
        // compute current chunk
        const s8* Bc = &Bsh[c & 1][0];
        const int code0 = cbase + c * 128;
#pragma unroll
        for (int j = 0; j < 4; ++j) {
            int rl = wc + j * 16 + lm;
            int nb = rl * 64;
            int sidx = (q ^ (rl & 3)) * 16;
            i32x4 bh = *reinterpret_cast<const i32x4*>(&Bc[0 * EPL8 + nb + sidx]);
            i32x4 bm = *reinterpret_cast<const i32x4*>(&Bc[1 * EPL8 + nb + sidx]);
            i32x4 bl = *reinterpret_cast<const i32x4*>(&Bc[2 * EPL8 + nb + sidx]);
            int code = code0 + rl;
#pragma unroll
            for (int i = 0; i < 4; ++i) {
                i32x4 A1 = (i32x4){0, 0, 0, 0};
                i32x4 A2 = (i32x4){0, 0, 0, 0};
                i32x4 A3 = (i32x4){0, 0, 0, 0};
                A1 = __builtin_amdgcn_mfma_i32_16x16x64_i8(a[0][i], bh, A1, 0, 0, 0);
                A2 = __builtin_amdgcn_mfma_i32_16x16x64_i8(a[0][i], bm, A2, 0, 0, 0);
                A2 = __builtin_amdgcn_mfma_i32_16x16x64_i8(a[1][i], bh, A2, 0, 0, 0);
                A3 = __builtin_amdgcn_mfma_i32_16x16x64_i8(a[0][i], bl, A3, 0, 0, 0);
                A3 = __builtin_amdgcn_mfma_i32_16x16x64_i8(a[2][i], bh, A3, 0, 0, 0);
                A3 = __builtin_amdgcn_mfma_i32_16x16x64_i8(a[1][i], bm, A3, 0, 0, 0);
#pragma unroll
                for (int r = 0; r < 4; ++r) {
                    // monotone int key: ((A1<<8)+A2)<<2 + (A3>>6)
                    int key = ((((A1[r] << 8) + A2[r]) << 2) + (A3[r] >> 6));
                    if (key > bkey[i][r]) { bkey[i][r] = key; bidx[i][r] = code; }
                }
            }
        }
        __syncthreads();   // next chunk landed + all waves done reading buf[c&1]
    }
    // reduce over the 16 lanes sharing each row (lm bits 0..3), stash winner
#pragma unroll
    for (int i = 0; i < 4; ++i)
#pragma unroll
        for (int r = 0; r < 4; ++r) {
            int v  = bkey[i][r];
            int id = bidx[i][r];
#pragma unroll
            for (int msk = 1; msk <= 8; msk <<= 1) {
                int ov  = __shfl_xor(v, msk, 64);
                int oid = __shfl_xor(id, msk, 64);
                if (ov > v || (ov == v && oid < id)) { v = ov; id = oid; }
            }
            if (lm == 0) {
                int rl = wr + i * 16 + q * 4 + r;
                sk[rl][w & 1] = v;
                si[rl][w & 1] = id;
            }
        }
    __syncthreads();
    if (t < 128) {
        int v0 = sk[t][0], v1 = sk[t][1];
        int i0 = si[t][0], i1 = si[t][1];
        int bv, bi;
        if (v1 > v0 || (v1 == v0 && i1 < i0)) { bv = v1; bi = i1; }
        else                                  { bv = v0; bi = i0; }
        pval[(size_t)(row0 + t) * 8 + split] = (float)bv;   // unused downstream
        pidx[(size_t)(row0 + t) * 8 + split] = bi;
    }
}

// ---------------------------------------------------------------------------
// Exact fp32 rescore of the 8 split candidates per row -> final idx,
// fused commitment loss (2 - 2*sim, unit vectors), and fused OUT GATHER:
// each wave, after the winner is known to ALL lanes (redundant LDS-broadcast
// recompute, no extra shuffle), copies P[idx] -> out[row] (64 lanes x 3
// float4 = 768 floats). Replaces the separate 16384-block gather_k launch.
// ORDERING: this kernel still completes before onehot_k overwrites the
// scratch region that holds P (round-5 invariant preserved).
// ---------------------------------------------------------------------------
__global__ __launch_bounds__(256) void merge_gather(const float* __restrict__ Zn,
                                                    const float* __restrict__ emb,
                                                    const int* __restrict__ pidx,
                                                    const float* __restrict__ P,
                                                    float* __restrict__ out,
                                                    int* __restrict__ idx,
                                                    float* __restrict__ loss) {
    __shared__ float sv[4][8];
    __shared__ int   si[4][8];
    const int t = threadIdx.x;
    const int w = t >> 6, lane = t & 63;
    const int row = blockIdx.x * 4 + w;
    const int cg = lane >> 3, s = lane & 7;
    int cand = pidx[(size_t)row * 8 + cg];
    const float4* zp = reinterpret_cast<const float4*>(Zn + (size_t)row * 64 + s * 8);
    const float4* ep = reinterpret_cast<const float4*>(emb + (size_t)cand * 64 + s * 8);
    float4 z0 = zp[0], z1 = zp[1], e0 = ep[0], e1 = ep[1];
    float acc = z0.x * e0.x + z0.y * e0.y + z0.z * e0.z + z0.w * e0.w
              + z1.x * e1.x + z1.y * e1.y + z1.z * e1.z + z1.w * e1.w;
#pragma unroll
    for (int msk = 1; msk <= 4; msk <<= 1) acc += __shfl_xor(acc, msk, 64);
    if (s == 0) { sv[w][cg] = acc; si[w][cg] = cand; }
    __syncthreads();
    // all lanes recompute the winner from LDS (same-address broadcast, free)
    float bv = sv[w][0];
    int   bi = si[w][0];
#pragma unroll
    for (int cc = 1; cc < 8; ++cc) {
        float v = sv[w][cc];
        int   ii = si[w][cc];
        if (v > bv || (v == bv && ii < bi)) { bv = v; bi = ii; }
    }
    if (lane == 0) {
        idx[row] = bi;
        // commitment loss: ||e - z||^2 = 2 - 2*<e,z> for unit vectors
        atomicAdd(loss, (2.0f - 2.0f * bv) * (1.0f / (16384.0f * 64.0f)));
    }
    // fused gather: out[row] = P[bi]  (768 floats = 64 lanes x 3 float4)
    const float4* src = reinterpret_cast<const float4*>(P + (size_t)bi * 768);
    float4* dst = reinterpret_cast<float4*>(out + (size_t)row * 768);
#pragma unroll
    for (int u = 0; u < 3; ++u) dst[u * 64 + lane] = src[u * 64 + lane];
}

// codex_probs: write the full one-hot matrix in one streaming pass.
// MUST run after merge_gather completes (P lives inside the codex scratch).
__global__ __launch_bounds__(256) void onehot_k(const int* __restrict__ idx,
                                                float* __restrict__ codex) {
    const int row = blockIdx.x;
    const int k = idx[row];
    float* base = codex + (size_t)row * 8192;
#pragma unroll
    for (int it = 0; it < 8; ++it) {
        int col = it * 1024 + threadIdx.x * 4;
        float4 v = {0.f, 0.f, 0.f, 0.f};
        unsigned d = (unsigned)(k - col);
        if (d < 4u) (&v.x)[d] = 1.0f;
        *reinterpret_cast<float4*>(base + col) = v;
    }
}

// ---------------------------------------------------------------------------
extern "C" void kernel_launch(void* const* d_in, const int* in_sizes, int n_in,
                              void* d_out, int out_size, void* d_ws, size_t ws_size,
                              hipStream_t stream) {
    const float* Z     = (const float*)d_in[0];
    const float* W1    = (const float*)d_in[1];
    const float* b1    = (const float*)d_in[2];
    const float* W2    = (const float*)d_in[3];
    const float* b2    = (const float*)d_in[4];
    const float* emb   = (const float*)d_in[5];
    const float* gamma = (const float*)d_in[6];
    const float* beta  = (const float*)d_in[7];
    const float* Wp    = (const float*)d_in[8];
    const float* bp    = (const float*)d_in[9];

    float* outF  = (float*)d_out;
    float* H     = outF + H_OFF;
    float* P     = outF + P_OFF;
    float* Zn    = outF + ZN_OFF;
    float* Q     = outF + Q_OFF;
    u16*   ZH    = (u16*)(outF + ZH_OFF);
    u16*   ZM    = (u16*)(outF + ZM_OFF);
    u16*   ZL    = (u16*)(outF + ZL_OFF);
    u16*   W1H   = (u16*)(outF + W1H_OFF);
    u16*   W1M   = (u16*)(outF + W1M_OFF);
    u16*   W1L   = (u16*)(outF + W1L_OFF);
    s8*    Z0    = (s8*)(outF + NH_OFF);
    s8*    Z1p   = (s8*)(outF + NM_OFF);
    s8*    Z2p   = (s8*)(outF + NL_OFF);
    s8*    E0    = (s8*)(outF + EH_OFF);
    s8*    E1    = (s8*)(outF + EM_OFF);
    s8*    E2    = (s8*)(outF + EL_OFF);
    float* lossp = outF + OUT_LOSS;
    float* codex = outF + OUT_CODEX;

    float* pval = (float*)d_ws;                       // 16384*8 floats
    int*   pidx = (int*)((char*)d_ws + 524288);       // 16384*8 ints
    int*   idxp = (int*)((char*)d_ws + 1048576);      // 16384 ints

    // fused preprocessing (split_z + split_w1t + qln_emb + loss zeroing)
    prep_k<<<8768, 256, 0, stream>>>(Z, ZH, ZM, ZL, W1, W1H, W1M, W1L,
                                     emb, gamma, beta, E0, E1, E2, Q, lossp);
    // H = tanh(Z @ W1 + b1)   (MFMA bf16x3, BN=192 -> 512 blocks, no tail)
    gemm1_mfma<<<512, 256, 0, stream>>>(ZH, ZM, ZL, W1H, W1M, W1L, b1, H);
    // fused: Zn = l2norm(H @ W2 + b2) + planes  ||  P = Q @ Wp + bp
    mid_k<<<640, 256, 0, stream>>>(H, W2, b2, Zn, Z0, Z1p, Z2p, Q, Wp, bp, P);
    // sim + per-split argmax (i8 MFMA, double-buffered emb staging)
    argmax_mfma<<<dim3(128, 8), 256, 0, stream>>>(Z0, Z1p, Z2p, E0, E1, E2, pval, pidx);
    // exact fp32 rescore -> idx + fused loss + fused out-gather
    merge_gather<<<4096, 256, 0, stream>>>(Zn, emb, pidx, P, outF, idxp, lossp);
    // codex one-hot (also wipes scratch region deterministically; AFTER gather)
    onehot_k<<<16384, 256, 0, stream>>>(idxp, codex);
}

// Round 13
// 1036.640 us; speedup vs baseline: 1.0784x; 1.0604x over previous
//
#include <hip/hip_runtime.h>
#include <cstddef>
#include <cstdint>

typedef unsigned short u16;
typedef signed char s8;
typedef short bf16x8 __attribute__((ext_vector_type(8)));
typedef float f32x4 __attribute__((ext_vector_type(4)));
typedef int i32x4 __attribute__((ext_vector_type(4)));

// Problem constants (B=16, S=1024, D=768, DC=64, K=8192)
#define NROW   16384
#define DMODEL 768
#define DCODE  64
#define KCODES 8192

// d_out layout (float element offsets): [out 16384*768][loss 1][codex 16384*8192]
#define OUT_LOSS  12582912
#define OUT_CODEX 12582913
// 16B-aligned scratch carved out of the codex region (fully overwritten by the
// one-hot writer at the end). All offsets in float units, multiples of 4.
// *** ORDERING INVARIANT: anything stored here (esp. P, Zn) must be fully
// *** consumed by dispatches that COMPLETE before the one-hot writer runs.
// *** When ws_size >= 32 MB, P and Zn move to d_ws, the invariant becomes
// *** vacuous for them, and one-hot fuses into merge_gather.
#define S0        12582916
#define H_OFF     (S0)                        // 12582912 f
#define P_OFF     (H_OFF + 12582912)          // 6291456 f
#define ZN_OFF    (P_OFF + 6291456)           // 1048576 f
#define Q_OFF     (ZN_OFF + 1048576)          // 524288 f
#define ZH_OFF    (Q_OFF + 524288)            // u16 planes of Z: each 12582912 u16 = 6291456 f
#define ZM_OFF    (ZH_OFF + 6291456)
#define ZL_OFF    (ZM_OFF + 6291456)
#define W1H_OFF   (ZL_OFF + 6291456)          // W1^T planes: each 589824 u16 = 294912 f
#define W1M_OFF   (W1H_OFF + 294912)
#define W1L_OFF   (W1M_OFF + 294912)
#define NH_OFF    (W1L_OFF + 294912)          // Zn i8 planes: each 1048576 B (region sized for 2x)
#define NM_OFF    (NH_OFF + 524288)
#define NL_OFF    (NM_OFF + 524288)
#define EH_OFF    (NL_OFF + 524288)           // emb i8 planes: each 524288 B (region sized for 2x)
#define EM_OFF    (EH_OFF + 262144)
#define EL_OFF    (EM_OFF + 262144)

__device__ __forceinline__ u16 f2bf(float x) {
    unsigned u = __float_as_uint(x);
    u += 0x7fffu + ((u >> 16) & 1u);          // RTNE
    return (u16)(u >> 16);
}
__device__ __forceinline__ float bf2f(u16 h) {
    return __uint_as_float(((unsigned)h) << 16);
}

// Exact 24-bit fixed-point split (scale 2^22, |x|<=1): x_q = h*2^16 + m*2^8 + l
__device__ __forceinline__ void f2i8x3(float x, int& h, int& m, int& l) {
    int q = (int)rintf(x * 4194304.0f);       // 2^22
    l = (q << 24) >> 24;
    int t = (q - l) >> 8;
    m = (t << 24) >> 24;
    h = (t - m) >> 8;                         // |h| <= 64
}

// async global->LDS, 16 B per lane. LDS dest is wave-uniform base + lane*16
// (m104/m108): callers must pass lds = base + lane*16 exactly.
typedef __attribute__((address_space(1))) const unsigned int gas_u32;
typedef __attribute__((address_space(3))) unsigned int las_u32;
__device__ __forceinline__ void gll16(const void* g, void* l) {
    __builtin_amdgcn_global_load_lds((gas_u32*)g, (las_u32*)l, 16, 0, 0);
}

// ---------------------------------------------------------------------------
// Fused preprocessing (one launch, block-range partitioned):
//   blocks [0, 6144)      : split Z -> 3 bf16 planes
//   blocks [6144, 6720)   : split+transpose W1 -> 3 bf16 planes (24x24 tiles)
//   blocks [6720, 8768)   : emb -> i8x3 planes + Q = LN(emb)*gamma+beta
// Block 6144 thread 0 also zeroes the loss accumulator (replaces memset).
// ---------------------------------------------------------------------------
__global__ __launch_bounds__(256) void prep_k(
        const float* __restrict__ Z,
        u16* __restrict__ Ph, u16* __restrict__ Pm, u16* __restrict__ Pl,
        const float* __restrict__ W1,
        u16* __restrict__ Th, u16* __restrict__ Tm, u16* __restrict__ Tl,
        const float* __restrict__ emb,
        const float* __restrict__ gamma, const float* __restrict__ beta,
        s8* __restrict__ E0, s8* __restrict__ E1, s8* __restrict__ E2,
        float* __restrict__ Q, float* __restrict__ loss) {
    __shared__ float tile[32][33];
    const int b = blockIdx.x;
    const int t = threadIdx.x;

    if (b < 6144) {
        // ---- split_z ----
        const size_t g = (size_t)b * 256 + t;   // x8 elements
        const float4* zp = reinterpret_cast<const float4*>(Z) + g * 2;
        float4 a = zp[0], bb = zp[1];
        float xs[8] = {a.x, a.y, a.z, a.w, bb.x, bb.y, bb.z, bb.w};
        union { u16 u[8]; uint4 v; } ph, pm, pl;
#pragma unroll
        for (int k = 0; k < 8; ++k) {
            float x = xs[k];
            u16 h = f2bf(x); float r = x - bf2f(h);
            u16 m = f2bf(r); float r2 = r - bf2f(m);
            u16 l = f2bf(r2);
            ph.u[k] = h; pm.u[k] = m; pl.u[k] = l;
        }
        *reinterpret_cast<uint4*>(Ph + g * 8) = ph.v;
        *reinterpret_cast<uint4*>(Pm + g * 8) = pm.v;
        *reinterpret_cast<uint4*>(Pl + g * 8) = pl.v;
    } else if (b < 6720) {
        // ---- split_w1t ----
        if (b == 6144 && t == 0) *loss = 0.0f;
        const int bb = b - 6144;
        const int k0 = (bb / 24) * 32, n0 = (bb % 24) * 32;
        const int tc = t & 31, tr = t >> 5;          // tr 0..7
#pragma unroll
        for (int rr = 0; rr < 4; ++rr) {
            int r = tr * 4 + rr;
            tile[r][tc] = W1[(size_t)(k0 + r) * 768 + n0 + tc];
        }
        __syncthreads();
#pragma unroll
        for (int rr = 0; rr < 4; ++rr) {
            int n = n0 + tr * 4 + rr;
            int k = k0 + tc;
            float x = tile[tc][tr * 4 + rr];
            u16 h = f2bf(x); float r = x - bf2f(h);
            u16 m = f2bf(r); u16 l = f2bf(r - bf2f(m));
            Th[(size_t)n * 768 + k] = h;
            Tm[(size_t)n * 768 + k] = m;
            Tl[(size_t)n * 768 + k] = l;
        }
    } else {
        // ---- qln_emb ----
        const int bb = b - 6720;
        const int lane = t & 63;
        const int n = bb * 4 + (t >> 6);
        float x = emb[(size_t)n * 64 + lane];
        int h8, m8, l8;
        f2i8x3(x, h8, m8, l8);
        E0[(size_t)n * 64 + lane] = (s8)h8;
        E1[(size_t)n * 64 + lane] = (s8)m8;
        E2[(size_t)n * 64 + lane] = (s8)l8;
        float mu = x;
#pragma unroll
        for (int off = 32; off > 0; off >>= 1) mu += __shfl_xor(mu, off, 64);
        mu *= (1.0f / 64.0f);
        float d = x - mu;
        float var = d * d;
#pragma unroll
        for (int off = 32; off > 0; off >>= 1) var += __shfl_xor(var, off, 64);
        var *= (1.0f / 64.0f);
        Q[(size_t)n * 64 + lane] = d * rsqrtf(var + 1e-5f) * gamma[lane] + beta[lane];
    }
}

// ---------------------------------------------------------------------------
// GEMM1 via 6-product bf16x3 MFMA: H = tanh(Z @ W1 + b1).
// M=16384, N=768, K=768. BM=128, BN=192, BK=32. 512 blocks = 2/CU, no tail.
// Per-element accumulation order fixed -> bitwise-stable H across rounds.
// ---------------------------------------------------------------------------
#define APL 4096    // u16 per 128x32 A plane tile
#define BPL 6144    // u16 per 192x32 B plane tile
#define BOFF (3 * APL)
__global__ __launch_bounds__(256, 2) void gemm1_mfma(
        const u16* __restrict__ Ah0, const u16* __restrict__ Am0, const u16* __restrict__ Al0,
        const u16* __restrict__ Bh0, const u16* __restrict__ Bm0, const u16* __restrict__ Bl0,
        const float* __restrict__ bias, float* __restrict__ H) {
    __shared__ u16 lds[3 * APL + 3 * BPL];    // A planes then B planes (61440 B)

    // 512 blocks: xcd = b&7, ii = b>>3 (0..63). Each XCD: 16 row-tiles x 4 col-tiles.
    const int b = blockIdx.x;
    const int xcd = b & 7, ii = b >> 3;
    const int row0 = (xcd * 16 + (ii & 15)) * 128;
    const int col0 = (ii >> 4) * 192;

    const int t = threadIdx.x;
    const int w = t >> 6, lane = t & 63, lm = lane & 15, q = lane >> 4;
    const int wr = (w >> 1) * 64, wc = (w & 1) * 96;

    const u16* Ap[3] = {Ah0, Am0, Al0};
    const u16* Bp[3] = {Bh0, Bm0, Bl0};

    // staging geometry: each wave-instruction covers 16 rows x 4 chunks(16B)
    const int sr  = lane >> 2;        // row within 16-row group
    const int scc = lane & 3;         // LDS chunk slot

    f32x4 acc[4][6];
#pragma unroll
    for (int i = 0; i < 4; ++i)
#pragma unroll
        for (int j = 0; j < 6; ++j) acc[i][j] = (f32x4){0.f, 0.f, 0.f, 0.f};

    for (int k0 = 0; k0 < 768; k0 += 32) {
        __syncthreads();
#pragma unroll
        for (int p = 0; p < 3; ++p) {
#pragma unroll
            for (int rr = 0; rr < 2; ++rr) {      // A: 8 groups of 16 rows
                int g = rr * 4 + w;
                int r = g * 16 + sr;              // local row 0..127
                int cg = scc ^ ((r >> 1) & 3);    // swizzled source chunk
                gll16(Ap[p] + (size_t)(row0 + r) * 768 + k0 + cg * 8,
                      &lds[p * APL + g * 512 + lane * 8]);
            }
#pragma unroll
            for (int rr = 0; rr < 3; ++rr) {      // B: 12 groups of 16 rows
                int g = rr * 4 + w;
                int r = g * 16 + sr;              // local row 0..191
                int cg = scc ^ ((r >> 1) & 3);
                gll16(Bp[p] + (size_t)(col0 + r) * 768 + k0 + cg * 8,
                      &lds[BOFF + p * BPL + g * 512 + lane * 8]);
            }
        }
        __syncthreads();

        bf16x8 fah[4], fam[4], fal[4];
#pragma unroll
        for (int i = 0; i < 4; ++i) {
            int r = wr + i * 16 + lm;
            int off = r * 32 + ((q ^ ((r >> 1) & 3)) * 8);
            fah[i] = *reinterpret_cast<const bf16x8*>(&lds[0 * APL + off]);
            fam[i] = *reinterpret_cast<const bf16x8*>(&lds[1 * APL + off]);
            fal[i] = *reinterpret_cast<const bf16x8*>(&lds[2 * APL + off]);
        }
#pragma unroll
        for (int j = 0; j < 6; ++j) {
            int rb = wc + j * 16 + lm;            // 0..191
            int offb = rb * 32 + ((q ^ ((rb >> 1) & 3)) * 8);
            bf16x8 fbh = *reinterpret_cast<const bf16x8*>(&lds[BOFF + 0 * BPL + offb]);
            bf16x8 fbm = *reinterpret_cast<const bf16x8*>(&lds[BOFF + 1 * BPL + offb]);
            bf16x8 fbl = *reinterpret_cast<const bf16x8*>(&lds[BOFF + 2 * BPL + offb]);
#pragma unroll
            for (int i = 0; i < 4; ++i) {
                f32x4 c = acc[i][j];
                c = __builtin_amdgcn_mfma_f32_16x16x32_bf16(fah[i], fbl, c, 0, 0, 0);
                c = __builtin_amdgcn_mfma_f32_16x16x32_bf16(fal[i], fbh, c, 0, 0, 0);
                c = __builtin_amdgcn_mfma_f32_16x16x32_bf16(fam[i], fbm, c, 0, 0, 0);
                c = __builtin_amdgcn_mfma_f32_16x16x32_bf16(fah[i], fbm, c, 0, 0, 0);
                c = __builtin_amdgcn_mfma_f32_16x16x32_bf16(fam[i], fbh, c, 0, 0, 0);
                c = __builtin_amdgcn_mfma_f32_16x16x32_bf16(fah[i], fbh, c, 0, 0, 0);
                acc[i][j] = c;
            }
        }
    }
    // epilogue: +bias, tanh, store
#pragma unroll
    for (int i = 0; i < 4; ++i)
#pragma unroll
        for (int j = 0; j < 6; ++j) {
            int col = col0 + wc + j * 16 + lm;
            float bv = bias[col];
#pragma unroll
            for (int r = 0; r < 4; ++r) {
                int row = row0 + wr + i * 16 + q * 4 + r;
                H[(size_t)row * 768 + col] = tanhf(acc[i][j][r] + bv);
            }
        }
}

// ---------------------------------------------------------------------------
// Fused mid-stage (one launch; the two parts are data-independent):
//   blocks [0,256)   : gemm2_l2 — Zn = l2norm(H @ W2 + b2) + i8x3 planes
//   blocks [256,640) : gemm128  — P = Q @ Wp + bp  (8192x768, K=64)
// ---------------------------------------------------------------------------
__global__ __launch_bounds__(256) void mid_k(
        const float* __restrict__ H, const float* __restrict__ W2,
        const float* __restrict__ b2, float* __restrict__ Zn,
        s8* __restrict__ Z0, s8* __restrict__ Z1, s8* __restrict__ Z2,
        const float* __restrict__ Q, const float* __restrict__ Wp,
        const float* __restrict__ bp, float* __restrict__ P) {
    __shared__ float smem[4096];              // 16 KB
    const int t = threadIdx.x;

    if (blockIdx.x < 256) {
        // ---- gemm2_l2 ----
        float (*As)[64] = reinterpret_cast<float(*)[64]>(smem);
        float (*Bs)[64] = reinterpret_cast<float(*)[64]>(smem + 1024);
        const int row0 = blockIdx.x * 64;
        const int tx = t & 15, ty = t >> 4;
        const int ar = t >> 2, ac = (t & 3) << 2;
        const int br = t >> 4, bc = (t & 15) << 2;

        const float* Ap = H + (size_t)(row0 + ar) * 768 + ac;
        const float* Bp = W2 + (size_t)br * 64 + bc;

        float acc[4][4];
#pragma unroll
        for (int i = 0; i < 4; ++i)
#pragma unroll
            for (int j = 0; j < 4; ++j) acc[i][j] = 0.0f;

        for (int k0 = 0; k0 < 768; k0 += 16) {
            float4 a0 = *reinterpret_cast<const float4*>(Ap + k0);
            float4 b0 = *reinterpret_cast<const float4*>(Bp + (size_t)k0 * 64);
            __syncthreads();
            As[ac + 0][ar] = a0.x; As[ac + 1][ar] = a0.y;
            As[ac + 2][ar] = a0.z; As[ac + 3][ar] = a0.w;
            *reinterpret_cast<float4*>(&Bs[br][bc]) = b0;
            __syncthreads();
#pragma unroll
            for (int k = 0; k < 16; ++k) {
                float4 xa = *reinterpret_cast<const float4*>(&As[k][ty << 2]);
                float4 xb = *reinterpret_cast<const float4*>(&Bs[k][tx << 2]);
                float av[4] = {xa.x, xa.y, xa.z, xa.w};
                float bv[4] = {xb.x, xb.y, xb.z, xb.w};
#pragma unroll
                for (int i = 0; i < 4; ++i)
#pragma unroll
                    for (int j = 0; j < 4; ++j)
                        acc[i][j] = fmaf(av[i], bv[j], acc[i][j]);
            }
        }
        const int c = tx << 2;
        const float4 bv4 = *reinterpret_cast<const float4*>(b2 + c);
#pragma unroll
        for (int i = 0; i < 4; ++i) {
            float v0 = acc[i][0] + bv4.x;
            float v1 = acc[i][1] + bv4.y;
            float v2 = acc[i][2] + bv4.z;
            float v3 = acc[i][3] + bv4.w;
            float ss = v0 * v0 + v1 * v1 + v2 * v2 + v3 * v3;
#pragma unroll
            for (int msk = 1; msk <= 8; msk <<= 1) ss += __shfl_xor(ss, msk, 64);
            float sc = 1.0f / fmaxf(sqrtf(ss), 1e-12f);
            v0 *= sc; v1 *= sc; v2 *= sc; v3 *= sc;
            int r = row0 + (ty << 2) + i;
            float4 z = {v0, v1, v2, v3};
            *reinterpret_cast<float4*>(Zn + (size_t)r * 64 + c) = z;
            float vs[4] = {v0, v1, v2, v3};
            unsigned pk0 = 0, pk1 = 0, pk2 = 0;
#pragma unroll
            for (int j = 0; j < 4; ++j) {
                int h8, m8, l8;
                f2i8x3(vs[j], h8, m8, l8);
                pk0 |= ((unsigned)(unsigned char)(s8)h8) << (8 * j);
                pk1 |= ((unsigned)(unsigned char)(s8)m8) << (8 * j);
                pk2 |= ((unsigned)(unsigned char)(s8)l8) << (8 * j);
            }
            *reinterpret_cast<unsigned*>(Z0 + (size_t)r * 64 + c) = pk0;
            *reinterpret_cast<unsigned*>(Z1 + (size_t)r * 64 + c) = pk1;
            *reinterpret_cast<unsigned*>(Z2 + (size_t)r * 64 + c) = pk2;
        }
    } else {
        // ---- gemm128: P = Q @ Wp + bp, M=8192, N=768, K=64 ----
        float (*As)[128] = reinterpret_cast<float(*)[128]>(smem);
        float (*Bs)[128] = reinterpret_cast<float(*)[128]>(smem + 2048);
        const int bb = blockIdx.x - 256;      // 0..383
        const int row0 = (bb / 6) * 128;
        const int col0 = (bb % 6) * 128;
        const int N = DMODEL, K = DCODE;
        const int tx = t & 15, ty = t >> 4;
        const int ar = t >> 2, ac = (t & 3) << 2;
        const int br = t >> 5, bc = (t & 31) << 2;

        const float* Ap0 = Q + (size_t)(row0 + ar) * K + ac;
        const float* Ap1 = Ap0 + (size_t)64 * K;
        const float* Bp0 = Wp + (size_t)br * N + col0 + bc;
        const float* Bp1 = Bp0 + (size_t)8 * N;

        float acc[8][8];
#pragma unroll
        for (int i = 0; i < 8; ++i)
#pragma unroll
            for (int j = 0; j < 8; ++j) acc[i][j] = 0.0f;

        for (int k0 = 0; k0 < K; k0 += 16) {
            float4 a0 = *reinterpret_cast<const float4*>(Ap0 + k0);
            float4 a1 = *reinterpret_cast<const float4*>(Ap1 + k0);
            float4 b0 = *reinterpret_cast<const float4*>(Bp0 + (size_t)k0 * N);
            float4 b1 = *reinterpret_cast<const float4*>(Bp1 + (size_t)k0 * N);
            __syncthreads();
            As[ac + 0][ar] = a0.x; As[ac + 1][ar] = a0.y;
            As[ac + 2][ar] = a0.z; As[ac + 3][ar] = a0.w;
            As[ac + 0][ar + 64] = a1.x; As[ac + 1][ar + 64] = a1.y;
            As[ac + 2][ar + 64] = a1.z; As[ac + 3][ar + 64] = a1.w;
            *reinterpret_cast<float4*>(&Bs[br][bc])     = b0;
            *reinterpret_cast<float4*>(&Bs[br + 8][bc]) = b1;
            __syncthreads();
#pragma unroll
            for (int k = 0; k < 16; ++k) {
                float4 xa0 = *reinterpret_cast<const float4*>(&As[k][ty << 2]);
                float4 xa1 = *reinterpret_cast<const float4*>(&As[k][(ty << 2) + 64]);
                float4 xb0 = *reinterpret_cast<const float4*>(&Bs[k][tx << 2]);
                float4 xb1 = *reinterpret_cast<const float4*>(&Bs[k][(tx << 2) + 64]);
                float av[8] = {xa0.x, xa0.y, xa0.z, xa0.w, xa1.x, xa1.y, xa1.z, xa1.w};
                float bv[8] = {xb0.x, xb0.y, xb0.z, xb0.w, xb1.x, xb1.y, xb1.z, xb1.w};
#pragma unroll
                for (int i = 0; i < 8; ++i)
#pragma unroll
                    for (int j = 0; j < 8; ++j)
                        acc[i][j] = fmaf(av[i], bv[j], acc[i][j]);
            }
        }
#pragma unroll
        for (int i = 0; i < 8; ++i) {
            int r = row0 + (ty << 2) + (i & 3) + ((i & 4) << 4);
            float* Crow = P + (size_t)r * N;
#pragma unroll
            for (int jh = 0; jh < 2; ++jh) {
                int cc = col0 + (tx << 2) + (jh << 6);
                float4 v;
                v.x = acc[i][jh * 4 + 0] + bp[cc + 0];
                v.y = acc[i][jh * 4 + 1] + bp[cc + 1];
                v.z = acc[i][jh * 4 + 2] + bp[cc + 2];
                v.w = acc[i][jh * 4 + 3] + bp[cc + 3];
                *reinterpret_cast<float4*>(Crow + cc) = v;
            }
        }
    }
}

// ---------------------------------------------------------------------------
// Sim + argmax via 6-product i8x3 fixed-point MFMA (mfma_i32_16x16x64_i8).
// Monotone integer key: key = (((A1<<8)+A2)<<2) + (A3>>6). Same product set
// and error bound as the verified round-3 kernel; MFMA order identical.
// DOUBLE-BUFFERED emb staging (2 x 24576 B, 2 blocks/CU at 102 KB).
// ---------------------------------------------------------------------------
#define EPL8 8192   // bytes per 128x64 i8 plane tile
__global__ __launch_bounds__(256, 2) void argmax_mfma(
        const s8* __restrict__ Z0, const s8* __restrict__ Z1, const s8* __restrict__ Z2,
        const s8* __restrict__ E0, const s8* __restrict__ E1, const s8* __restrict__ E2,
        float* __restrict__ pval, int* __restrict__ pidx) {
    __shared__ __align__(16) s8 Bsh[2][3 * EPL8];   // 49152 B double-buffered
    __shared__ int sk[128][2];
    __shared__ int si[128][2];
    const int rb = blockIdx.x, split = blockIdx.y;
    const int row0 = rb * 128, cbase = split * 1024;
    const int t = threadIdx.x;
    const int w = t >> 6, lane = t & 63, lm = lane & 15, q = lane >> 4;
    const int wr = (w >> 1) * 64, wc = (w & 1) * 64;

    // staging geometry: each wave-instruction covers 16 rows x 4 chunks(16B)
    const int sr  = lane >> 2;        // row within 16-row group
    const int scc = lane & 3;         // LDS chunk slot

    // Resident A fragments: [plane][mtile], 16 contiguous k-bytes per lane
    i32x4 a[3][4];
#pragma unroll
    for (int i = 0; i < 4; ++i) {
        int row = row0 + wr + i * 16 + lm;
        size_t off = (size_t)row * 64 + q * 16;
        a[0][i] = *reinterpret_cast<const i32x4*>(Z0 + off);
        a[1][i] = *reinterpret_cast<const i32x4*>(Z1 + off);
        a[2][i] = *reinterpret_cast<const i32x4*>(Z2 + off);
    }

    // prologue: stage chunk 0 -> buf 0
#pragma unroll
    for (int p = 0; p < 3; ++p) {
        const s8* Ep = (p == 0) ? E0 : ((p == 1) ? E1 : E2);
#pragma unroll
        for (int rr = 0; rr < 2; ++rr) {
            int g = rr * 4 + w;            // 16-row group 0..7
            int r = g * 16 + sr;           // local code row 0..127
            int cg = scc ^ (r & 3);        // swizzled source chunk
            gll16(Ep + (size_t)(cbase + r) * 64 + cg * 16,
                  &Bsh[0][p * EPL8 + g * 1024 + lane * 16]);
        }
    }
    __syncthreads();

    int bkey[4][4];
    int bidx[4][4];
#pragma unroll
    for (int i = 0; i < 4; ++i)
#pragma unroll
        for (int r = 0; r < 4; ++r) { bkey[i][r] = (int)0x80000000; bidx[i][r] = 0; }

    for (int c = 0; c < 8; ++c) {
        // stage next chunk into the other buffer (loads fly under compute)
        if (c < 7) {
            const int code0n = cbase + (c + 1) * 128;
            s8* dst = &Bsh[(c + 1) & 1][0];
#pragma unroll
            for (int p = 0; p < 3; ++p) {
                const s8* Ep = (p == 0) ? E0 : ((p == 1) ? E1 : E2);
#pragma unroll
                for (int rr = 0; rr < 2; ++rr) {
                    int g = rr * 4 + w;
                    int r = g * 16 + sr;
                    int cg = scc ^ (r & 3);
                    gll16(Ep + (size_t)(code0n + r) * 64 + cg * 16,
                          dst + p * EPL8 + g * 1024 + lane * 16);
                }
            }
        }
        // compute current chunk
        const s8* Bc = &Bsh[c & 1][0];
        const int code0 = cbase + c * 128;
#pragma unroll
        for (int j = 0; j < 4; ++j) {
            int rl = wc + j * 16 + lm;
            int nb = rl * 64;
            int sidx = (q ^ (rl & 3)) * 16;
            i32x4 bh = *reinterpret_cast<const i32x4*>(&Bc[0 * EPL8 + nb + sidx]);
            i32x4 bm = *reinterpret_cast<const i32x4*>(&Bc[1 * EPL8 + nb + sidx]);
            i32x4 bl = *reinterpret_cast<const i32x4*>(&Bc[2 * EPL8 + nb + sidx]);
            int code = code0 + rl;
#pragma unroll
            for (int i = 0; i < 4; ++i) {
                i32x4 A1 = (i32x4){0, 0, 0, 0};
                i32x4 A2 = (i32x4){0, 0, 0, 0};
                i32x4 A3 = (i32x4){0, 0, 0, 0};
                A1 = __builtin_amdgcn_mfma_i32_16x16x64_i8(a[0][i], bh, A1, 0, 0, 0);
                A2 = __builtin_amdgcn_mfma_i32_16x16x64_i8(a[0][i], bm, A2, 0, 0, 0);
                A2 = __builtin_amdgcn_mfma_i32_16x16x64_i8(a[1][i], bh, A2, 0, 0, 0);
                A3 = __builtin_amdgcn_mfma_i32_16x16x64_i8(a[0][i], bl, A3, 0, 0, 0);
                A3 = __builtin_amdgcn_mfma_i32_16x16x64_i8(a[2][i], bh, A3, 0, 0, 0);
                A3 = __builtin_amdgcn_mfma_i32_16x16x64_i8(a[1][i], bm, A3, 0, 0, 0);
#pragma unroll
                for (int r = 0; r < 4; ++r) {
                    // monotone int key: ((A1<<8)+A2)<<2 + (A3>>6)
                    int key = ((((A1[r] << 8) + A2[r]) << 2) + (A3[r] >> 6));
                    if (key > bkey[i][r]) { bkey[i][r] = key; bidx[i][r] = code; }
                }
            }
        }
        __syncthreads();   // next chunk landed + all waves done reading buf[c&1]
    }
    // reduce over the 16 lanes sharing each row (lm bits 0..3), stash winner
#pragma unroll
    for (int i = 0; i < 4; ++i)
#pragma unroll
        for (int r = 0; r < 4; ++r) {
            int v  = bkey[i][r];
            int id = bidx[i][r];
#pragma unroll
            for (int msk = 1; msk <= 8; msk <<= 1) {
                int ov  = __shfl_xor(v, msk, 64);
                int oid = __shfl_xor(id, msk, 64);
                if (ov > v || (ov == v && oid < id)) { v = ov; id = oid; }
            }
            if (lm == 0) {
                int rl = wr + i * 16 + q * 4 + r;
                sk[rl][w & 1] = v;
                si[rl][w & 1] = id;
            }
        }
    __syncthreads();
    if (t < 128) {
        int v0 = sk[t][0], v1 = sk[t][1];
        int i0 = si[t][0], i1 = si[t][1];
        int bv, bi;
        if (v1 > v0 || (v1 == v0 && i1 < i0)) { bv = v1; bi = i1; }
        else                                  { bv = v0; bi = i0; }
        pval[(size_t)(row0 + t) * 8 + split] = (float)bv;   // unused downstream
        pidx[(size_t)(row0 + t) * 8 + split] = bi;
    }
}

// ---------------------------------------------------------------------------
// merge_core: exact fp32 rescore of 8 candidates -> winner known to ALL lanes
// (redundant LDS-broadcast recompute), fused commitment loss + out-gather.
// Shared by both tail variants below.
// ---------------------------------------------------------------------------
__device__ __forceinline__ int merge_core(const float* __restrict__ Zn,
                                          const float* __restrict__ emb,
                                          const int* __restrict__ pidx,
                                          const float* __restrict__ P,
                                          float* __restrict__ out,
                                          int* __restrict__ idx,
                                          float* __restrict__ loss,
                                          float* sv, int* si,
                                          int row, int w, int lane) {
    const int cg = lane >> 3, s = lane & 7;
    int cand = pidx[(size_t)row * 8 + cg];
    const float4* zp = reinterpret_cast<const float4*>(Zn + (size_t)row * 64 + s * 8);
    const float4* ep = reinterpret_cast<const float4*>(emb + (size_t)cand * 64 + s * 8);
    float4 z0 = zp[0], z1 = zp[1], e0 = ep[0], e1 = ep[1];
    float acc = z0.x * e0.x + z0.y * e0.y + z0.z * e0.z + z0.w * e0.w
              + z1.x * e1.x + z1.y * e1.y + z1.z * e1.z + z1.w * e1.w;
#pragma unroll
    for (int msk = 1; msk <= 4; msk <<= 1) acc += __shfl_xor(acc, msk, 64);
    if (s == 0) { sv[w * 8 + cg] = acc; si[w * 8 + cg] = cand; }
    __syncthreads();
    // all lanes recompute the winner from LDS (same-address broadcast, free)
    float bv = sv[w * 8 + 0];
    int   bi = si[w * 8 + 0];
#pragma unroll
    for (int cc = 1; cc < 8; ++cc) {
        float v = sv[w * 8 + cc];
        int   ii = si[w * 8 + cc];
        if (v > bv || (v == bv && ii < bi)) { bv = v; bi = ii; }
    }
    if (lane == 0) {
        idx[row] = bi;
        // commitment loss: ||e - z||^2 = 2 - 2*<e,z> for unit vectors
        atomicAdd(loss, (2.0f - 2.0f * bv) * (1.0f / (16384.0f * 64.0f)));
    }
    // fused gather: out[row] = P[bi]  (768 floats = 64 lanes x 3 float4)
    const float4* src = reinterpret_cast<const float4*>(P + (size_t)bi * 768);
    float4* dst = reinterpret_cast<float4*>(out + (size_t)row * 768);
#pragma unroll
    for (int u = 0; u < 3; ++u) dst[u * 64 + lane] = src[u * 64 + lane];
    return bi;
}

// Variant A (fallback, P/Zn in codex scratch): rescore+loss+gather only.
// onehot_k MUST run afterwards as a separate dispatch (round-5 invariant).
__global__ __launch_bounds__(256) void merge_gather(const float* __restrict__ Zn,
                                                    const float* __restrict__ emb,
                                                    const int* __restrict__ pidx,
                                                    const float* __restrict__ P,
                                                    float* __restrict__ out,
                                                    int* __restrict__ idx,
                                                    float* __restrict__ loss) {
    __shared__ float sv[32];
    __shared__ int   si[32];
    const int t = threadIdx.x;
    const int w = t >> 6, lane = t & 63;
    const int row = blockIdx.x * 4 + w;
    merge_core(Zn, emb, pidx, P, out, idx, loss, sv, si, row, w, lane);
}

// Variant B (big-ws: P and Zn live in d_ws -> NOT in the codex scratch, so
// the one-hot write cannot clobber any of this kernel's inputs): rescore +
// loss + gather + one-hot row write, all in one launch. Replaces onehot_k.
__global__ __launch_bounds__(256) void merge_gather_oh(const float* __restrict__ Zn,
                                                       const float* __restrict__ emb,
                                                       const int* __restrict__ pidx,
                                                       const float* __restrict__ P,
                                                       float* __restrict__ out,
                                                       int* __restrict__ idx,
                                                       float* __restrict__ loss,
                                                       float* __restrict__ codex) {
    __shared__ float sv[32];
    __shared__ int   si[32];
    const int t = threadIdx.x;
    const int w = t >> 6, lane = t & 63;
    const int row = blockIdx.x * 4 + w;
    int bi = merge_core(Zn, emb, pidx, P, out, idx, loss, sv, si, row, w, lane);
    // one-hot row: 8192 floats = 32 iters x 64 lanes x float4 (same bytes as
    // the old onehot_k, per-wave instead of per-block)
    float* base = codex + (size_t)row * 8192;
#pragma unroll
    for (int it = 0; it < 32; ++it) {
        int col = it * 256 + lane * 4;
        float4 v = {0.f, 0.f, 0.f, 0.f};
        unsigned d = (unsigned)(bi - col);
        if (d < 4u) (&v.x)[d] = 1.0f;
        *reinterpret_cast<float4*>(base + col) = v;
    }
}

// codex_probs: full one-hot matrix (fallback path only).
// MUST run after merge_gather completes (P/Zn live inside the codex scratch).
__global__ __launch_bounds__(256) void onehot_k(const int* __restrict__ idx,
                                                float* __restrict__ codex) {
    const int row = blockIdx.x;
    const int k = idx[row];
    float* base = codex + (size_t)row * 8192;
#pragma unroll
    for (int it = 0; it < 8; ++it) {
        int col = it * 1024 + threadIdx.x * 4;
        float4 v = {0.f, 0.f, 0.f, 0.f};
        unsigned d = (unsigned)(k - col);
        if (d < 4u) (&v.x)[d] = 1.0f;
        *reinterpret_cast<float4*>(base + col) = v;
    }
}

// ---------------------------------------------------------------------------
extern "C" void kernel_launch(void* const* d_in, const int* in_sizes, int n_in,
                              void* d_out, int out_size, void* d_ws, size_t ws_size,
                              hipStream_t stream) {
    const float* Z     = (const float*)d_in[0];
    const float* W1    = (const float*)d_in[1];
    const float* b1    = (const float*)d_in[2];
    const float* W2    = (const float*)d_in[3];
    const float* b2    = (const float*)d_in[4];
    const float* emb   = (const float*)d_in[5];
    const float* gamma = (const float*)d_in[6];
    const float* beta  = (const float*)d_in[7];
    const float* Wp    = (const float*)d_in[8];
    const float* bp    = (const float*)d_in[9];

    float* outF  = (float*)d_out;
    float* H     = outF + H_OFF;
    float* Q     = outF + Q_OFF;
    u16*   ZH    = (u16*)(outF + ZH_OFF);
    u16*   ZM    = (u16*)(outF + ZM_OFF);
    u16*   ZL    = (u16*)(outF + ZL_OFF);
    u16*   W1H   = (u16*)(outF + W1H_OFF);
    u16*   W1M   = (u16*)(outF + W1M_OFF);
    u16*   W1L   = (u16*)(outF + W1L_OFF);
    s8*    Z0    = (s8*)(outF + NH_OFF);
    s8*    Z1p   = (s8*)(outF + NM_OFF);
    s8*    Z2p   = (s8*)(outF + NL_OFF);
    s8*    E0    = (s8*)(outF + EH_OFF);
    s8*    E1    = (s8*)(outF + EM_OFF);
    s8*    E2    = (s8*)(outF + EL_OFF);
    float* lossp = outF + OUT_LOSS;
    float* codex = outF + OUT_CODEX;

    float* pval = (float*)d_ws;                       // 16384*8 floats @ 0
    int*   pidx = (int*)((char*)d_ws + 524288);       // 16384*8 ints  @ 512K
    int*   idxp = (int*)((char*)d_ws + 1048576);      // 16384 ints    @ 1M

    // ws layout for big-ws path: Zn @ 2M (4 MB), P @ 8M (24 MB) -> need 32 MB.
    const bool big_ws = ws_size >= (size_t)33554432;
    float* Zn = big_ws ? (float*)((char*)d_ws + 2097152) : outF + ZN_OFF;
    float* P  = big_ws ? (float*)((char*)d_ws + 8388608) : outF + P_OFF;

    // fused preprocessing (split_z + split_w1t + qln_emb + loss zeroing)
    prep_k<<<8768, 256, 0, stream>>>(Z, ZH, ZM, ZL, W1, W1H, W1M, W1L,
                                     emb, gamma, beta, E0, E1, E2, Q, lossp);
    // H = tanh(Z @ W1 + b1)   (MFMA bf16x3, BN=192 -> 512 blocks, no tail)
    gemm1_mfma<<<512, 256, 0, stream>>>(ZH, ZM, ZL, W1H, W1M, W1L, b1, H);
    // fused: Zn = l2norm(H @ W2 + b2) + planes  ||  P = Q @ Wp + bp
    mid_k<<<640, 256, 0, stream>>>(H, W2, b2, Zn, Z0, Z1p, Z2p, Q, Wp, bp, P);
    // sim + per-split argmax (i8 MFMA, double-buffered emb staging)
    argmax_mfma<<<dim3(128, 8), 256, 0, stream>>>(Z0, Z1p, Z2p, E0, E1, E2, pval, pidx);
    if (big_ws) {
        // P/Zn in ws -> one-hot can fuse with rescore+gather (no scratch race)
        merge_gather_oh<<<4096, 256, 0, stream>>>(Zn, emb, pidx, P, outF, idxp,
                                                  lossp, codex);
    } else {
        // fallback: identical to the round-10 verified path
        merge_gather<<<4096, 256, 0, stream>>>(Zn, emb, pidx, P, outF, idxp, lossp);
        onehot_k<<<16384, 256, 0, stream>>>(idxp, codex);
    }
}